// Round 9
// baseline (1201.065 us; speedup 1.0000x reference)
//
#include <hip/hip_runtime.h>
#include <math.h>

#define BB 16
#define LL 48
#define HH 1024
#define NG4 4096      // 4*H
#define NG6 6144      // 6*H
#define K3H 3072      // 3*H
#define RANKH 128
#define MAXN 47       // max nodes per batch (len-1 <= 47)
#define TOTN (BB*MAXN)
#define MAXLVL 48
#define MAXNPL 384    // max nodes in one level

#define FSTRIDE 32    // dwords between flag lines (128B line spacing)
#define FDOM 8192     // dwords per barrier domain (tree uses flags+FDOM)
#define HS_S 1028     // padded LDS row stride (floats) for h-stage

typedef __attribute__((ext_vector_type(8))) short bf16x8;
typedef __attribute__((ext_vector_type(4))) float f32x4;

__device__ __forceinline__ float sigf(float x){ return 1.f/(1.f + expf(-x)); }

__device__ __forceinline__ unsigned short f2bf(float f){
  union { float f; unsigned u; } v; v.f = f;
  unsigned r = v.u + 0x7fff + ((v.u >> 16) & 1);
  return (unsigned short)(r >> 16);
}

// ---- LLC-coherent ops (device coherence point; bypass L1/L2, no allocate) ----
__device__ __forceinline__ void st_llc(float* p, float v){
  __hip_atomic_store(p, v, __ATOMIC_RELAXED, __HIP_MEMORY_SCOPE_AGENT);
}
__device__ __forceinline__ float ld_llc(const float* p){
  return __hip_atomic_load(p, __ATOMIC_RELAXED, __HIP_MEMORY_SCOPE_AGENT);
}
__device__ __forceinline__ void st_llc_u16(unsigned short* p, unsigned v){
  asm volatile("global_store_short %0, %1, off sc0 sc1" :: "v"(p), "v"(v) : "memory");
}
__device__ __forceinline__ void st_llc_u32(unsigned* p, unsigned v){
  asm volatile("global_store_dword %0, %1, off sc0 sc1" :: "v"(p), "v"(v) : "memory");
}
__device__ __forceinline__ void wait_vm0(){
  asm volatile("s_waitcnt vmcnt(0)" ::: "memory");
}

// Distributed-flag grid barrier (R4/R6 variant — the only mechanism that has
// passed correctness on this part; atomic-RMW barriers corrupted twice, with
// and without model fences, and are condemned here). Each block owns a
// PRIVATE 128B line; arrival stores land in parallel across LLC banks.
// Thread i polls flags[i*FSTRIDE]; 4-wave __all + LDS reduce. Data crossing
// the barrier must use LLC ops (st_llc*) or be first-read-after-write.
// flags MUST be zeroed every launch (workspace re-poisoned each run).
__device__ __forceinline__ void flagbar(unsigned* flags, unsigned p, int* ldsok){
  wait_vm0();
  __syncthreads();
  int tid = threadIdx.x;
  if (tid == 0)
    st_llc_u32(&flags[blockIdx.x*FSTRIDE], p);
  for (;;){
    unsigned v;
    asm volatile("global_load_dword %0, %1, off sc0 sc1"
                 : "=v"(v) : "v"(&flags[tid*FSTRIDE]));
    wait_vm0();
    int all64 = __all((int)(v >= p));
    if ((tid & 63) == 0) ldsok[tid >> 6] = all64;
    __syncthreads();
    if (ldsok[0] & ldsok[1] & ldsok[2] & ldsok[3]) break;
    __builtin_amdgcn_s_sleep(1);
    __syncthreads();
  }
}

// ---------------------------------------------------------------------------
// Zero flag domains + the zero dummy row.
__global__ __launch_bounds__(256) void k_init(unsigned* flags, unsigned short* zrow){
  int tid = threadIdx.x;
  for (int i = tid; i < 2*FDOM; i += 256) flags[i] = 0u;
  for (int i = tid; i < 1024; i += 256) zrow[i] = 0;
}

// ---------------------------------------------------------------------------
// fp32 -> bf16 (RNE), vectorized. n multiple of 1024.
__global__ __launch_bounds__(256) void k_cvt_bf16(const float* __restrict__ in,
    unsigned short* __restrict__ out, int n){
  int i = (blockIdx.x*256 + threadIdx.x)*4;
  if (i >= n) return;
  float4 v = *(const float4*)(in + i);
  ushort4 o;
  o.x = f2bf(v.x); o.y = f2bf(v.y); o.z = f2bf(v.z); o.w = f2bf(v.w);
  *(ushort4*)(out + i) = o;
}

// ---------------------------------------------------------------------------
// Generic 32x32 LDS-tiled transpose: out[C][R] = in[R][C]^T  (R1 only)
__global__ __launch_bounds__(256) void k_transpose(const float* __restrict__ in,
                                                   float* __restrict__ out, int R, int C){
  __shared__ float t[32][33];
  int bx = blockIdx.x*32, by = blockIdx.y*32;
  int x = threadIdx.x, y = threadIdx.y;   // block (32,8)
  #pragma unroll
  for (int i = 0; i < 32; i += 8){
    int r = by + y + i, c = bx + x;
    if (r < R && c < C) t[y+i][x] = in[(size_t)r*C + c];
  }
  __syncthreads();
  #pragma unroll
  for (int i = 0; i < 32; i += 8){
    int r = bx + y + i, c = by + x;       // out dims [C][R]
    if (r < C && c < R) out[(size_t)r*R + c] = t[x][y+i];
  }
}

// ---------------------------------------------------------------------------
// Gx[m][n] = sum_k se[m][k]*Wih[n][k] + bih[n] + bhh[n]   (fp32 — decision path)
__global__ __launch_bounds__(256) void k_gemm_gx(const float* __restrict__ A,
    const float* __restrict__ Bw, const float* __restrict__ bih,
    const float* __restrict__ bhh, float* __restrict__ Cout, int M, int N, int K){
  __shared__ float as[16][68];
  __shared__ float bs[16][68];
  int m0 = blockIdx.x*64, n0 = blockIdx.y*64;
  int tid = threadIdx.x;
  int mt = tid & 15, nt = tid >> 4;
  float acc[4][4] = {};
  for (int k0 = 0; k0 < K; k0 += 16){
    #pragma unroll
    for (int it = 0; it < 4; ++it){
      int idx = it*256 + tid;
      int kk = idx & 15, mm = idx >> 4;
      as[kk][mm] = A[(size_t)(m0+mm)*K + k0 + kk];
      bs[kk][mm] = Bw[(size_t)(n0+mm)*K + k0 + kk];
    }
    __syncthreads();
    #pragma unroll
    for (int kk = 0; kk < 16; ++kk){
      float a4[4], b4[4];
      #pragma unroll
      for (int i = 0; i < 4; ++i) a4[i] = as[kk][mt*4+i];
      #pragma unroll
      for (int i = 0; i < 4; ++i) b4[i] = bs[kk][nt*4+i];
      #pragma unroll
      for (int i = 0; i < 4; ++i)
        #pragma unroll
        for (int j2 = 0; j2 < 4; ++j2) acc[i][j2] += a4[i]*b4[j2];
    }
    __syncthreads();
  }
  #pragma unroll
  for (int i = 0; i < 4; ++i){
    int m = m0 + mt*4 + i;
    #pragma unroll
    for (int j2 = 0; j2 < 4; ++j2){
      int n = n0 + nt*4 + j2;
      Cout[(size_t)m*N + n] = acc[i][j2] + bih[n] + bhh[n];
    }
  }
}

// ---------------------------------------------------------------------------
// Gx [m][t][4096] -> Gxt [t][4096][m]  (for coalesced per-step gate reads)
__global__ __launch_bounds__(256) void k_gx_t(const float* __restrict__ Gx,
                                              float* __restrict__ Gxt){
  __shared__ float t2[16][257];
  int t = blockIdx.x;       // 48
  int rc = blockIdx.y;      // 16 chunks of 256 rows
  int tid = threadIdx.x;
  #pragma unroll
  for (int m = 0; m < 16; ++m)
    t2[m][tid] = Gx[((size_t)(m*48 + t))*4096 + rc*256 + tid];
  __syncthreads();
  int rl = tid >> 4, m = tid & 15;
  #pragma unroll
  for (int i = 0; i < 16; ++i){
    int r = rc*256 + i*16 + rl;
    Gxt[((size_t)t*4096 + r)*16 + m] = t2[m][i*16 + rl];
  }
}

// ---------------------------------------------------------------------------
// ONE LSTM time step as its own kernel launch. 256 blocks x 256 threads.
// The KERNEL BOUNDARY is the grid barrier: kernel-end flushes dirty L2,
// kernel-start invalidates caches (mechanism empirically validated by the
// plain-store hs/cs/hs_bf -> plain-load k_score/k_tree path, which passed
// across rounds). Everything here is PLAIN memory:
//  - h_{t-1}: contiguous cached dwordx4 reads of hx[t-1] slab (dispatch
//    invalidate -> fresh; L2-shared within each XCD)
//  - Whh register slice: reloaded each launch; block->XCD mapping is
//    deterministic per identical grid, so the 16MB re-read is L2-warm
//  - h_t / c-state / hs / cs / hs_bf: plain cached stores (kernel-end flush)
// Whh regs PERMUTED to the [m][k] LDS layout:
//   lane kc owns k-indices {r*256 + 4*kc + j : r=0..3, j=0..3}
__global__ __launch_bounds__(256, 1) void k_lstm_step(
    const float* __restrict__ Whh, const float* __restrict__ Gxt,
    float* __restrict__ hx,
    float* __restrict__ hs, float* __restrict__ cs,
    unsigned short* __restrict__ hs_bf, float* __restrict__ cstate, int t){
  __shared__ float smem[17408];   // 68KB: h-stage [16][HS_S]; overlaid by reduce partials
  __shared__ float gbuf[4*64];
  int tid = threadIdx.x;
  int g = tid >> 6, kc = tid & 63;
  int j0 = blockIdx.x * 4;
  // per-launch Whh slice load (L2-warm after step 0)
  float w[4][16];
  #pragma unroll
  for (int jj = 0; jj < 4; ++jj){
    const float* src = Whh + (size_t)(g*1024 + j0 + jj)*1024 + kc*4;
    #pragma unroll
    for (int r = 0; r < 4; ++r){
      float4 v = *(const float4*)(src + r*256);
      w[jj][r*4+0]=v.x; w[jj][r*4+1]=v.y; w[jj][r*4+2]=v.z; w[jj][r*4+3]=v.w;
    }
  }
  // x-gate contribution for gate group g (read-only, cached)
  float gx = Gxt[((size_t)t*NG4 + g*1024 + j0 + (kc & 3))*16 + (kc >> 2)];
  float G = 0.f;
  if (t > 0){
    // h_{t-1}: contiguous 64KB slab read (fully coalesced dwordx4)
    const float* slab = hx + (size_t)(t-1)*16384;
    f32x4 hv[16];
    #pragma unroll
    for (int i = 0; i < 16; ++i)
      hv[i] = *(const f32x4*)(slab + i*1024 + tid*4);
    // LDS transpose [j][m] -> [m][j]  (m=(tid&3)*4+e, j=i*64+(tid>>2))
    {
      int mb = (tid & 3) * 4;
      int jb = tid >> 2;
      #pragma unroll
      for (int i = 0; i < 16; ++i){
        #pragma unroll
        for (int e = 0; e < 4; ++e)
          smem[(size_t)(mb + e)*HS_S + i*64 + jb] = hv[i][e];
      }
    }
    __syncthreads();
    float acc[4][16];
    #pragma unroll 4
    for (int m = 0; m < 16; ++m){
      const float* hb = &smem[(size_t)m*HS_S + (kc<<2)];
      float4 h0 = *(const float4*)(hb);        // canonical b128: lanes at 16B stride
      float4 h1 = *(const float4*)(hb+256);
      float4 h2 = *(const float4*)(hb+512);
      float4 h3 = *(const float4*)(hb+768);
      #pragma unroll
      for (int jj = 0; jj < 4; ++jj){
        float s = w[jj][0]*h0.x + w[jj][1]*h0.y + w[jj][2]*h0.z + w[jj][3]*h0.w
                + w[jj][4]*h1.x + w[jj][5]*h1.y + w[jj][6]*h1.z + w[jj][7]*h1.w
                + w[jj][8]*h2.x + w[jj][9]*h2.y + w[jj][10]*h2.z + w[jj][11]*h2.w
                + w[jj][12]*h3.x + w[jj][13]*h3.y + w[jj][14]*h3.z + w[jj][15]*h3.w;
        acc[jj][m] = s;
      }
    }
    __syncthreads();   // h reads done; smem reused as reduce partials
    #pragma unroll
    for (int m = 0; m < 16; ++m){
      float4 v;
      v.x = acc[0][m]; v.y = acc[1][m]; v.z = acc[2][m]; v.w = acc[3][m];
      *(float4*)&smem[(size_t)(g*64 + kc)*68 + m*4] = v;
    }
    __syncthreads();
    {
      float s0=0.f,s1=0.f,s2=0.f,s3=0.f;
      #pragma unroll 4
      for (int l = 0; l < 64; l += 4){
        s0 += smem[(size_t)(g*64 + l  )*68 + kc];
        s1 += smem[(size_t)(g*64 + l+1)*68 + kc];
        s2 += smem[(size_t)(g*64 + l+2)*68 + kc];
        s3 += smem[(size_t)(g*64 + l+3)*68 + kc];
      }
      G = (s0+s1)+(s2+s3);
    }
  }
  gbuf[g*64 + kc] = G + gx;   // recurrent + input parts combined
  __syncthreads();
  if (g == 0){
    int o = kc;                       // o = jj*16 + m (coalesced hx order)
    int jj = o >> 4, m = o & 15;
    int op = m*4 + jj;                // gbuf/cstate slot (value for (m,jj))
    float gi = gbuf[0*64 + op];
    float gf = gbuf[1*64 + op];
    float gu = gbuf[2*64 + op];
    float go = gbuf[3*64 + op];
    float cp = (t > 0) ? cstate[blockIdx.x*64 + op] : 0.f;
    float c = sigf(gf)*cp + sigf(gi)*tanhf(gu);
    float h = sigf(go)*tanhf(c);
    cstate[blockIdx.x*64 + op] = c;
    // cross-step exchange + outputs: ALL plain stores (kernel-end flush)
    hx[(size_t)t*16384 + j0*16 + o] = h;
    size_t oidx = ((size_t)(m*LL + t))*HH + j0 + jj;
    hs[oidx] = h;
    cs[oidx] = c;
    hs_bf[oidx] = f2bf(h);
  }
}

// ---------------------------------------------------------------------------
// Per-position rank-MLP score + gumbel noise (fp32 — decision path).
__global__ __launch_bounds__(128) void k_score(const float* __restrict__ R1t,
    const float* __restrict__ R2, const float* __restrict__ hs,
    const float* __restrict__ gumbel_u, float* __restrict__ score,
    float* __restrict__ snoisy){
  __shared__ float hsm[HH];
  __shared__ float red[128];
  int bt = blockIdx.x;
  int tid = threadIdx.x;
  for (int i = tid; i < HH; i += 128) hsm[i] = hs[(size_t)bt*HH + i];
  __syncthreads();
  float acc = 0.f;
  for (int k = 0; k < HH; ++k) acc += R1t[(size_t)k*RANKH + tid] * hsm[k];
  red[tid] = fmaxf(acc, 0.f) * R2[tid];
  __syncthreads();
  for (int s = 64; s > 0; s >>= 1){
    if (tid < s) red[tid] += red[tid+s];
    __syncthreads();
  }
  if (tid == 0){
    float s = red[0];
    float u = gumbel_u[bt];
    float noise = -logf(-logf(u));
    score[bt]  = s;
    snoisy[bt] = s + noise;
  }
}

// ---------------------------------------------------------------------------
// Build the tree structure for all batches. 1 block, 64 threads.
// level_count[0] <- number of levels (max height).
__global__ __launch_bounds__(64) void k_build(const float* __restrict__ score,
    const float* __restrict__ snoisy, const int* __restrict__ length,
    int* __restrict__ node_l, int* __restrict__ node_r, int* __restrict__ node_x,
    int* __restrict__ node_lvl, int* __restrict__ node_b, int* __restrict__ node_root,
    int* __restrict__ level_count, int* __restrict__ level_off, int* __restrict__ order){
  __shared__ float sc[BB*LL], sn[BB*LL];
  __shared__ int lcount[MAXLVL+1], lcur[MAXLVL+1], loff[MAXLVL+1];
  __shared__ int percnt[BB];
  int tid = threadIdx.x;
  for (int i = tid; i < BB*LL; i += 64){ sc[i] = score[i]; sn[i] = snoisy[i]; }
  for (int i = tid; i <= MAXLVL; i += 64){ lcount[i] = 0; lcur[i] = 0; }
  __syncthreads();
  if (tid < BB){
    int b = tid;
    int len = length[b];
    if (len > LL) len = LL;
    int qs[MAXN], qe[MAXN], qn[MAXN];
    int qh = 0, qt = 0, cnt = 0;
    int rootn = cnt++;
    qs[qt] = 0; qe[qt] = len; qn[qt] = rootn; qt++;
    while (qh < qt){
      int s0 = qs[qh], e0 = qe[qh], nid = qn[qh]; qh++;
      float best = sc[b*LL + s0]; int pos = s0;
      for (int t2 = s0+1; t2 < e0; ++t2){
        float v = sc[b*LL + t2];
        if (v > best){ best = v; pos = t2; }
      }
      float bestn = sn[b*LL + s0]; int js = s0;
      for (int t2 = s0+1; t2 < e0; ++t2){
        float v = sn[b*LL + t2];
        if (v > bestn){ bestn = v; js = t2; }
      }
      int gid = b*MAXN + nid;
      node_x[gid] = js;
      node_b[gid] = b;
      node_root[gid] = (nid == 0) ? 1 : 0;
      int ln = pos - s0, enc_l, enc_r;
      if (ln <= 0) enc_l = -1;
      else if (ln == 1) enc_l = 10000 + s0;
      else { int c2 = cnt++; enc_l = b*MAXN + c2; qs[qt]=s0; qe[qt]=pos; qn[qt]=c2; qt++; }
      int rn = e0 - (pos+1);
      if (rn <= 0) enc_r = -1;
      else if (rn == 1) enc_r = 10000 + (pos+1);
      else { int c2 = cnt++; enc_r = b*MAXN + c2; qs[qt]=pos+1; qe[qt]=e0; qn[qt]=c2; qt++; }
      node_l[gid] = enc_l; node_r[gid] = enc_r;
    }
    for (int i = cnt-1; i >= 0; --i){
      int gid = b*MAXN + i;
      int el = node_l[gid], er = node_r[gid];
      int llv = (el >= 0 && el < 10000) ? node_lvl[el] : 0;
      int rlv = (er >= 0 && er < 10000) ? node_lvl[er] : 0;
      node_lvl[gid] = 1 + (llv > rlv ? llv : rlv);
    }
    for (int i = 0; i < cnt; ++i) atomicAdd(&lcount[node_lvl[b*MAXN + i]], 1);
    percnt[b] = cnt;
  }
  __syncthreads();
  if (tid == 0){
    int off = 0, nlev = 0;
    for (int lv = 1; lv <= MAXLVL; ++lv){
      loff[lv] = off;
      level_off[lv] = off;
      level_count[lv] = lcount[lv];
      if (lcount[lv] > 0) nlev = lv;
      off += lcount[lv];
    }
    level_count[0] = nlev;
  }
  __syncthreads();
  if (tid < BB){
    int b = tid;
    int cnt = percnt[b];
    for (int i = 0; i < cnt; ++i){
      int gid = b*MAXN + i;
      int lv = node_lvl[gid];
      int p = atomicAdd(&lcur[lv], 1);
      order[loff[lv] + p] = gid;
    }
  }
}

// ---------------------------------------------------------------------------
// Persistent tree composition, distributed-flag barriers (R6-exact), NO wb/inv.
// Wc is LDS-RESIDENT: each of the 256 blocks owns 24 Wc rows (144KB, loaded
// once, XOR-swizzled). Per level every block computes its 24 gate columns for
// ALL nodes of the level; A-frags are L2-broadcast reads, B from LDS.
// Coherence protocol:
//  - gates: LLC stores (A) -> LLC loads (B)
//  - nodeH_bf / nodeC: LLC stores (B) -> normal cached first-reads later
//  - Wc_bf / hs_bf / order / node_*: read-only, cached.
__global__ __launch_bounds__(256, 1) void k_tree(
    const unsigned short* __restrict__ Wc_bf,
    const unsigned short* __restrict__ hs_bf,
    unsigned short* __restrict__ nodeH_bf,
    const unsigned short* __restrict__ zrow,
    const float* __restrict__ bc, const float* __restrict__ cs,
    float* __restrict__ nodeC,
    const int* __restrict__ node_l, const int* __restrict__ node_r,
    const int* __restrict__ node_x, const int* __restrict__ node_b,
    const int* __restrict__ node_root, const int* __restrict__ level_count,
    const int* __restrict__ level_off, const int* __restrict__ order,
    float* __restrict__ gates, float* __restrict__ out,
    unsigned* __restrict__ flags){
  __shared__ __align__(16) unsigned char wlds[24*6144];   // 144KB Wc slice
  __shared__ int ldsok[4];
  int tid = threadIdx.x;
  int lane = tid & 63;
  int wave = tid >> 6;
  int fr = lane & 15;          // fragment row (A: node slot, B: Wc row)
  int fkq = lane >> 4;         // k-quarter 0..3
  int fk  = fkq * 8;           // element offset within 32-elem k-chunk
  int fkb = fkq * 16;          // byte offset
  int swz = (fr & 7) << 4;     // XOR swizzle (G4: row-major stride-6144B tile)
  int base0 = fr * 6144;               // n-tile 0: rows 0..15
  int base1 = (16 + (fr & 7)) * 6144;  // n-tile 1: rows 16..23 (dup for fr>=8)
  int rg24 = blockIdx.x * 24;  // this block's 24 Wc rows / gate columns

  // ---- one-time: stage 24 Wc rows into LDS, swizzled ----
  for (int i = tid; i < 24*384; i += 256){
    int row = i / 384;
    int ch  = i - row*384;     // 16B chunk within row
    uint4 v = *(const uint4*)(Wc_bf + (size_t)(rg24 + row)*K3H + ch*8);
    *(uint4*)(wlds + row*6144 + ((ch*16) ^ ((row & 7) << 4))) = v;
  }
  __syncthreads();

  int nlev = level_count[0];
  unsigned ph = 0;
  for (int lvl = 1; lvl <= nlev; ++lvl){
    int n = level_count[lvl];
    int loffv = level_off[lvl];
    // ---- Phase A: all nodes x this block's 24 Wc rows, B from LDS ----
    int mtiles = (n + 15) >> 4;
    for (int mt = wave; mt < mtiles; mt += 4){
      int slot = mt*16 + fr;
      const unsigned short *pa0, *pa1, *pa2;
      if (slot < n){
        int gid = order[loffv + slot];
        int b = node_b[gid];
        int el = node_l[gid], er = node_r[gid], xt = node_x[gid];
        pa0 = (el < 0) ? zrow : (el >= 10000 ? hs_bf + (size_t)(b*LL + (el-10000))*HH
                                             : nodeH_bf + (size_t)el*HH);
        pa1 = (er < 0) ? zrow : (er >= 10000 ? hs_bf + (size_t)(b*LL + (er-10000))*HH
                                             : nodeH_bf + (size_t)er*HH);
        pa2 = hs_bf + (size_t)(b*LL + xt)*HH;
      } else { pa0 = zrow; pa1 = zrow; pa2 = zrow; }
      const unsigned short* pa[3] = {pa0, pa1, pa2};
      f32x4 acc0 = {0.f,0.f,0.f,0.f};
      f32x4 acc1 = {0.f,0.f,0.f,0.f};
      #pragma unroll
      for (int part = 0; part < 3; ++part){
        const unsigned short* ap = pa[part] + fk;
        #pragma unroll 8
        for (int kcc = 0; kcc < 1024; kcc += 32){
          bf16x8 a = *(const bf16x8*)(ap + kcc);
          int xb = part*2048 + kcc*2 + fkb;
          bf16x8 b0 = *(const bf16x8*)(wlds + base0 + (xb ^ swz));
          bf16x8 b1 = *(const bf16x8*)(wlds + base1 + (xb ^ swz));
          acc0 = __builtin_amdgcn_mfma_f32_16x16x32_bf16(a, b0, acc0, 0, 0, 0);
          acc1 = __builtin_amdgcn_mfma_f32_16x16x32_bf16(a, b1, acc1, 0, 0, 0);
        }
      }
      int m0 = mt*16 + fkq*4;
      #pragma unroll
      for (int r = 0; r < 4; ++r){
        int m = m0 + r;
        if (m < n){
          st_llc(&gates[(size_t)m*NG6 + rg24 + fr], acc0[r]);
          if (fr < 8)
            st_llc(&gates[(size_t)m*NG6 + rg24 + 16 + fr], acc1[r]);
        }
      }
    }
    ph++;
    flagbar(flags, ph, ldsok);
    // ---- Phase B: epilogue ----
    int items = n * 4;
    for (int it = blockIdx.x; it < items; it += 256){
      int ns = it >> 2;
      int j = (it & 3)*256 + tid;
      int gid = order[loffv + ns];
      int b = node_b[gid];
      int el = node_l[gid], er = node_r[gid], xt = node_x[gid];
      float gg[6];
      #pragma unroll
      for (int q = 0; q < 6; ++q)
        gg[q] = bc[q*HH + j] + ld_llc(&gates[(size_t)ns*NG6 + q*HH + j]);
      float lc = (el < 0) ? 0.f : (el >= 10000 ? cs[(size_t)(b*LL + (el-10000))*HH + j]
                                               : nodeC[(size_t)el*HH + j]);
      float rc = (er < 0) ? 0.f : (er >= 10000 ? cs[(size_t)(b*LL + (er-10000))*HH + j]
                                               : nodeC[(size_t)er*HH + j]);
      float xc = cs[(size_t)(b*LL + xt)*HH + j];
      float c = sigf(gg[0])*tanhf(gg[4]) + sigf(gg[1])*lc + sigf(gg[2])*rc + sigf(gg[3])*xc;
      float h = sigf(gg[5])*tanhf(c);
      st_llc_u16(&nodeH_bf[(size_t)gid*HH + j], (unsigned)f2bf(h));
      st_llc(&nodeC[(size_t)gid*HH + j], c);
      if (node_root[gid]){
        out[(size_t)b*HH + j] = h;
        out[(size_t)BB*HH + (size_t)b*HH + j] = c;
      }
    }
    if (lvl < nlev){
      ph++;
      flagbar(flags, ph, ldsok);
    }
  }
}

// ---------------------------------------------------------------------------
extern "C" void kernel_launch(void* const* d_in, const int* in_sizes, int n_in,
                              void* d_out, int out_size, void* d_ws, size_t ws_size,
                              hipStream_t stream){
  const float* se  = (const float*)d_in[0];
  const float* gu  = (const float*)d_in[1];
  const float* Wih = (const float*)d_in[2];
  const float* Whh = (const float*)d_in[3];
  const float* bih = (const float*)d_in[4];
  const float* bhh = (const float*)d_in[5];
  const float* R1  = (const float*)d_in[6];
  const float* R2  = (const float*)d_in[7];
  const float* Wc  = (const float*)d_in[8];
  const float* bc  = (const float*)d_in[9];
  const int*   len = (const int*)d_in[10];
  float* out = (float*)d_out;                 // [2,16,1024] fp32

  float* ws = (float*)d_ws;
  size_t off = 0;
  float* R1t   = ws + off; off += (size_t)HH*RANKH;
  float* Gx    = ws + off; off += (size_t)BB*LL*NG4;     // [m][t][4096]
  float* Gxt   = ws + off; off += (size_t)BB*LL*NG4;     // [t][4096][m]
  float* hx    = ws + off; off += (size_t)LL*HH*BB;      // [t][j][m] exchange (3MB)
  float* hs    = ws + off; off += (size_t)BB*LL*HH;
  float* cs    = ws + off; off += (size_t)BB*LL*HH;
  float* nodeC = ws + off; off += (size_t)TOTN*HH;
  float* gates = ws + off; off += (size_t)MAXNPL*NG6;
  float* cstate = ws + off; off += 256*64;               // per-block c carry
  unsigned short* Wc_bf    = (unsigned short*)(ws + off); off += (size_t)NG6*K3H/2;
  unsigned short* hs_bf    = (unsigned short*)(ws + off); off += (size_t)BB*LL*HH/2;
  unsigned short* nodeH_bf = (unsigned short*)(ws + off); off += (size_t)TOTN*HH/2 + 512;
  unsigned short* zrow     = (unsigned short*)(ws + off); off += 512;  // 1024 zero bf16
  float* score = ws + off; off += 1024;
  float* snoi  = ws + off; off += 1024;
  unsigned* flags = (unsigned*)(ws + off); off += 2*FDOM; // tree uses flags+FDOM
  int* ib = (int*)(ws + off);
  int* node_l    = ib; ib += 768;
  int* node_r    = ib; ib += 768;
  int* node_x    = ib; ib += 768;
  int* node_lvl  = ib; ib += 768;
  int* node_b    = ib; ib += 768;
  int* node_root = ib; ib += 768;
  int* level_count = ib; ib += 64;
  int* level_off   = ib; ib += 64;
  int* order       = ib; ib += 768;

  // 0. zero flag arrays + dummy zero row (ws poisoned every launch)
  k_init<<<1, 256, 0, stream>>>(flags, zrow);
  // 1. R1 transpose + Wc bf16 conversion
  k_transpose<<<dim3(32, 4), dim3(32, 8), 0, stream>>>(R1, R1t, RANKH, HH);
  k_cvt_bf16<<<(NG6*K3H)/1024, 256, 0, stream>>>(Wc, Wc_bf, NG6*K3H);
  // 2. input-side gate GEMM (+ both biases), then transpose for the scan
  k_gemm_gx<<<dim3(12, 64), 256, 0, stream>>>(se, Wih, bih, bhh, Gx, BB*LL, NG4, HH);
  k_gx_t<<<dim3(48, 16), 256, 0, stream>>>(Gx, Gxt);
  // 3. recurrent LSTM scan: ONE KERNEL PER STEP (kernel boundary = barrier)
  for (int t = 0; t < LL; ++t)
    k_lstm_step<<<256, 256, 0, stream>>>(Whh, Gxt, hx, hs, cs, hs_bf, cstate, t);
  // 4. per-position scores + gumbel noise (fp32)
  k_score<<<BB*LL, 128, 0, stream>>>(R1t, R2, hs, gu, score, snoi);
  // 5. tree structure
  k_build<<<1, 64, 0, stream>>>(score, snoi, len, node_l, node_r, node_x,
                                node_lvl, node_b, node_root,
                                level_count, level_off, order);
  // 6. persistent level-by-level nary composition (flag barriers, R6-exact)
  k_tree<<<256, 256, 0, stream>>>(Wc_bf, hs_bf, nodeH_bf, zrow, bc, cs, nodeC,
                                  node_l, node_r, node_x, node_b, node_root,
                                  level_count, level_off, order,
                                  gates, out, flags + FDOM);
}

// Round 10
// 1072.943 us; speedup vs baseline: 1.1194x; 1.1194x over previous
//
#include <hip/hip_runtime.h>
#include <math.h>

#define BB 16
#define LL 48
#define HH 1024
#define NG4 4096      // 4*H
#define NG6 6144      // 6*H
#define K3H 3072      // 3*H
#define RANKH 128
#define MAXN 47       // max nodes per batch (len-1 <= 47)
#define TOTN (BB*MAXN)
#define MAXLVL 48
#define MAXNPL 384    // max nodes in one level

#define FSTRIDE 32    // dwords between flag lines (128B line spacing)
#define FDOM 8192     // dwords per barrier domain (scan @0, tree @FDOM)
#define HS_S 1028     // padded LDS row stride (floats) for h-stage

typedef __attribute__((ext_vector_type(8))) short bf16x8;
typedef __attribute__((ext_vector_type(4))) float f32x4;

__device__ __forceinline__ float sigf(float x){ return 1.f/(1.f + expf(-x)); }

__device__ __forceinline__ unsigned short f2bf(float f){
  union { float f; unsigned u; } v; v.f = f;
  unsigned r = v.u + 0x7fff + ((v.u >> 16) & 1);
  return (unsigned short)(r >> 16);
}
__device__ __forceinline__ float bf2f(unsigned short h){
  union { unsigned u; float f; } v; v.u = ((unsigned)h) << 16;
  return v.f;
}

// ---- LLC-coherent ops (device coherence point; bypass L1/L2, no allocate) ----
__device__ __forceinline__ void st_llc(float* p, float v){
  __hip_atomic_store(p, v, __ATOMIC_RELAXED, __HIP_MEMORY_SCOPE_AGENT);
}
__device__ __forceinline__ float ld_llc(const float* p){
  return __hip_atomic_load(p, __ATOMIC_RELAXED, __HIP_MEMORY_SCOPE_AGENT);
}
__device__ __forceinline__ void st_llc_u16(unsigned short* p, unsigned v){
  asm volatile("global_store_short %0, %1, off sc0 sc1" :: "v"(p), "v"(v) : "memory");
}
__device__ __forceinline__ void st_llc_u32(unsigned* p, unsigned v){
  asm volatile("global_store_dword %0, %1, off sc0 sc1" :: "v"(p), "v"(v) : "memory");
}
__device__ __forceinline__ void wait_vm0(){
  asm volatile("s_waitcnt vmcnt(0)" ::: "memory");
}

// Distributed-flag grid barrier (R4/R6 variant — the only mechanism that has
// passed correctness on this part; atomic-RMW barriers corrupted twice, with
// and without model fences, and are condemned here; per-step kernel launches
// cost ~10us each and lost to this). Each block owns a PRIVATE 128B line;
// arrival stores land in parallel across LLC banks. Thread i polls
// flags[i*FSTRIDE]; 4-wave __all + LDS reduce. Data crossing the barrier must
// use LLC ops (st_llc*) or be first-read-after-write. flags MUST be zeroed
// every launch (workspace re-poisoned each run).
__device__ __forceinline__ void flagbar(unsigned* flags, unsigned p, int* ldsok){
  wait_vm0();
  __syncthreads();
  int tid = threadIdx.x;
  if (tid == 0)
    st_llc_u32(&flags[blockIdx.x*FSTRIDE], p);
  for (;;){
    unsigned v;
    asm volatile("global_load_dword %0, %1, off sc0 sc1"
                 : "=v"(v) : "v"(&flags[tid*FSTRIDE]));
    wait_vm0();
    int all64 = __all((int)(v >= p));
    if ((tid & 63) == 0) ldsok[tid >> 6] = all64;
    __syncthreads();
    if (ldsok[0] & ldsok[1] & ldsok[2] & ldsok[3]) break;
    __builtin_amdgcn_s_sleep(1);
    __syncthreads();
  }
}

// ---------------------------------------------------------------------------
// Zero both flag domains + the zero dummy row.
__global__ __launch_bounds__(256) void k_init(unsigned* flags, unsigned short* zrow){
  int tid = threadIdx.x;
  for (int i = tid; i < 2*FDOM; i += 256) flags[i] = 0u;
  for (int i = tid; i < 1024; i += 256) zrow[i] = 0;
}

// ---------------------------------------------------------------------------
// fp32 -> bf16 (RNE), vectorized. n multiple of 1024.
__global__ __launch_bounds__(256) void k_cvt_bf16(const float* __restrict__ in,
    unsigned short* __restrict__ out, int n){
  int i = (blockIdx.x*256 + threadIdx.x)*4;
  if (i >= n) return;
  float4 v = *(const float4*)(in + i);
  ushort4 o;
  o.x = f2bf(v.x); o.y = f2bf(v.y); o.z = f2bf(v.z); o.w = f2bf(v.w);
  *(ushort4*)(out + i) = o;
}

// ---------------------------------------------------------------------------
// fp32 -> (hi, lo) bf16 split: v = hi + lo + O(2^-18 v). n multiple of 1024.
__global__ __launch_bounds__(256) void k_split(const float* __restrict__ in,
    unsigned short* __restrict__ hi, unsigned short* __restrict__ lo, int n){
  int i = (blockIdx.x*256 + threadIdx.x)*4;
  if (i >= n) return;
  float4 v = *(const float4*)(in + i);
  ushort4 h, l;
  h.x = f2bf(v.x); h.y = f2bf(v.y); h.z = f2bf(v.z); h.w = f2bf(v.w);
  l.x = f2bf(v.x - bf2f(h.x)); l.y = f2bf(v.y - bf2f(h.y));
  l.z = f2bf(v.z - bf2f(h.z)); l.w = f2bf(v.w - bf2f(h.w));
  *(ushort4*)(hi + i) = h;
  *(ushort4*)(lo + i) = l;
}

// ---------------------------------------------------------------------------
// Generic 32x32 LDS-tiled transpose: out[C][R] = in[R][C]^T  (R1 only)
__global__ __launch_bounds__(256) void k_transpose(const float* __restrict__ in,
                                                   float* __restrict__ out, int R, int C){
  __shared__ float t[32][33];
  int bx = blockIdx.x*32, by = blockIdx.y*32;
  int x = threadIdx.x, y = threadIdx.y;   // block (32,8)
  #pragma unroll
  for (int i = 0; i < 32; i += 8){
    int r = by + y + i, c = bx + x;
    if (r < R && c < C) t[y+i][x] = in[(size_t)r*C + c];
  }
  __syncthreads();
  #pragma unroll
  for (int i = 0; i < 32; i += 8){
    int r = bx + y + i, c = by + x;       // out dims [C][R]
    if (r < C && c < R) out[(size_t)r*R + c] = t[x][y+i];
  }
}

// ---------------------------------------------------------------------------
// Gx[m][n] = sum_k se[m][k]*Wih[n][k] + bih[n] + bhh[n] via MFMA with hi/lo
// bf16 split (3-term: hi*hi + lo*hi + hi*lo; error ~1e-4 absolute — safe for
// the decision path, 100x tighter than raw bf16). M=768, N=4096, K=1024.
// Tile 64x64, 4 waves; wave w owns m-rows [m0+w*16, +16), 4 n-groups of 16.
// A/B frags loaded directly from global (L1/L2-fed; tiles are cache-resident).
// Fragment/output mapping mirrors k_tree's verified pattern:
//   A lane fr -> row, fkq -> k-quarter; output row = fkq*4+r, col = fr.
__global__ __launch_bounds__(256) void k_gemm_gx_mfma(
    const unsigned short* __restrict__ Ah, const unsigned short* __restrict__ Al,
    const unsigned short* __restrict__ Bh, const unsigned short* __restrict__ Bl,
    const float* __restrict__ bih, const float* __restrict__ bhh,
    float* __restrict__ Gx){
  int tid = threadIdx.x;
  int lane = tid & 63, wave = tid >> 6;
  int fr = lane & 15, fkq = lane >> 4, fk = fkq*8;
  int m0 = blockIdx.x*64 + wave*16;
  int n0 = blockIdx.y*64;
  const unsigned short* ah = Ah + (size_t)(m0 + fr)*1024 + fk;
  const unsigned short* al = Al + (size_t)(m0 + fr)*1024 + fk;
  const unsigned short* bh0 = Bh + (size_t)(n0 + fr)*1024 + fk;
  const unsigned short* bl0 = Bl + (size_t)(n0 + fr)*1024 + fk;
  f32x4 acc[4] = {{0.f,0.f,0.f,0.f},{0.f,0.f,0.f,0.f},
                  {0.f,0.f,0.f,0.f},{0.f,0.f,0.f,0.f}};
  for (int kc = 0; kc < 1024; kc += 32){
    bf16x8 a1 = *(const bf16x8*)(ah + kc);
    bf16x8 a2 = *(const bf16x8*)(al + kc);
    #pragma unroll
    for (int ng = 0; ng < 4; ++ng){
      bf16x8 b1 = *(const bf16x8*)(bh0 + (size_t)ng*16*1024 + kc);
      bf16x8 b2 = *(const bf16x8*)(bl0 + (size_t)ng*16*1024 + kc);
      acc[ng] = __builtin_amdgcn_mfma_f32_16x16x32_bf16(a1, b1, acc[ng], 0, 0, 0);
      acc[ng] = __builtin_amdgcn_mfma_f32_16x16x32_bf16(a2, b1, acc[ng], 0, 0, 0);
      acc[ng] = __builtin_amdgcn_mfma_f32_16x16x32_bf16(a1, b2, acc[ng], 0, 0, 0);
    }
  }
  #pragma unroll
  for (int ng = 0; ng < 4; ++ng)
    #pragma unroll
    for (int r = 0; r < 4; ++r){
      int m = m0 + fkq*4 + r;
      int n = n0 + ng*16 + fr;
      Gx[(size_t)m*NG4 + n] = acc[ng][r] + bih[n] + bhh[n];
    }
}

// ---------------------------------------------------------------------------
// Gx [m][t][4096] -> Gxt [t][4096][m]  (for coalesced per-step gate reads)
__global__ __launch_bounds__(256) void k_gx_t(const float* __restrict__ Gx,
                                              float* __restrict__ Gxt){
  __shared__ float t2[16][257];
  int t = blockIdx.x;       // 48
  int rc = blockIdx.y;      // 16 chunks of 256 rows
  int tid = threadIdx.x;
  #pragma unroll
  for (int m = 0; m < 16; ++m)
    t2[m][tid] = Gx[((size_t)(m*48 + t))*4096 + rc*256 + tid];
  __syncthreads();
  int rl = tid >> 4, m = tid & 15;
  #pragma unroll
  for (int i = 0; i < 16; ++i){
    int r = rc*256 + i*16 + rl;
    Gxt[((size_t)t*4096 + r)*16 + m] = t2[m][i*16 + rl];
  }
}

// ---------------------------------------------------------------------------
// Persistent LSTM scan: 256 blocks x 256 threads, 1 block/CU. (R6-exact:
// best measured passing config, 486us.) Cross-step h via hx[t][j][m]:
// producer tail writes ONE contiguous 256B st_llc burst; consumers read the
// 64KB slab with contiguous cached dwordx4 (first-read-after-write -> fresh
// LLC lines, L2-shared per XCD), then LDS-transpose [j][m]->[m][j].
// hs/cs/hs_bf are consumed by later kernels only -> plain cached stores.
// Whh registers PERMUTED to the [m][k] layout:
//   lane kc owns k-indices {r*256 + 4*kc + j : r=0..3, j=0..3}
__global__ __launch_bounds__(256, 1) void k_lstm_scan(
    const float* __restrict__ Whh, const float* __restrict__ Gxt,
    float* __restrict__ hx,
    float* __restrict__ hs, float* __restrict__ cs,
    unsigned short* __restrict__ hs_bf, unsigned* __restrict__ flags){
  __shared__ float smem[17408];   // 68KB: h-stage [16][HS_S]; overlaid by reduce partials
  __shared__ float gbuf[4*64];
  __shared__ float cbuf[64];
  __shared__ int ldsok[4];
  int tid = threadIdx.x;
  int g = tid >> 6, kc = tid & 63;
  int j0 = blockIdx.x * 4;
  float w[4][16];
  #pragma unroll
  for (int jj = 0; jj < 4; ++jj){
    const float* src = Whh + (size_t)(g*1024 + j0 + jj)*1024 + kc*4;
    #pragma unroll
    for (int r = 0; r < 4; ++r){
      float4 v = *(const float4*)(src + r*256);
      w[jj][r*4+0]=v.x; w[jj][r*4+1]=v.y; w[jj][r*4+2]=v.z; w[jj][r*4+3]=v.w;
    }
  }
  if (tid < 64) cbuf[tid] = 0.f;
  for (int t = 0; t < LL; ++t){
    float gx = Gxt[((size_t)t*NG4 + g*1024 + j0 + (kc & 3))*16 + (kc >> 2)];
    float G = 0.f;
    if (t > 0){
      const float* slab = hx + (size_t)(t-1)*16384;
      f32x4 hv[16];
      #pragma unroll
      for (int i = 0; i < 16; ++i)
        hv[i] = *(const f32x4*)(slab + i*1024 + tid*4);
      {
        int mb = (tid & 3) * 4;
        int jb = tid >> 2;
        #pragma unroll
        for (int i = 0; i < 16; ++i){
          #pragma unroll
          for (int e = 0; e < 4; ++e)
            smem[(size_t)(mb + e)*HS_S + i*64 + jb] = hv[i][e];
        }
      }
      __syncthreads();
      float acc[4][16];
      #pragma unroll 4
      for (int m = 0; m < 16; ++m){
        const float* hb = &smem[(size_t)m*HS_S + (kc<<2)];
        float4 h0 = *(const float4*)(hb);
        float4 h1 = *(const float4*)(hb+256);
        float4 h2 = *(const float4*)(hb+512);
        float4 h3 = *(const float4*)(hb+768);
        #pragma unroll
        for (int jj = 0; jj < 4; ++jj){
          float s = w[jj][0]*h0.x + w[jj][1]*h0.y + w[jj][2]*h0.z + w[jj][3]*h0.w
                  + w[jj][4]*h1.x + w[jj][5]*h1.y + w[jj][6]*h1.z + w[jj][7]*h1.w
                  + w[jj][8]*h2.x + w[jj][9]*h2.y + w[jj][10]*h2.z + w[jj][11]*h2.w
                  + w[jj][12]*h3.x + w[jj][13]*h3.y + w[jj][14]*h3.z + w[jj][15]*h3.w;
          acc[jj][m] = s;
        }
      }
      __syncthreads();   // h reads done; smem reused as reduce partials
      #pragma unroll
      for (int m = 0; m < 16; ++m){
        float4 v;
        v.x = acc[0][m]; v.y = acc[1][m]; v.z = acc[2][m]; v.w = acc[3][m];
        *(float4*)&smem[(size_t)(g*64 + kc)*68 + m*4] = v;
      }
      __syncthreads();
      {
        float s0=0.f,s1=0.f,s2=0.f,s3=0.f;
        #pragma unroll 4
        for (int l = 0; l < 64; l += 4){
          s0 += smem[(size_t)(g*64 + l  )*68 + kc];
          s1 += smem[(size_t)(g*64 + l+1)*68 + kc];
          s2 += smem[(size_t)(g*64 + l+2)*68 + kc];
          s3 += smem[(size_t)(g*64 + l+3)*68 + kc];
        }
        G = (s0+s1)+(s2+s3);
      }
    }
    gbuf[g*64 + kc] = G + gx;
    __syncthreads();
    if (g == 0){
      int o = kc;                       // o = jj*16 + m (coalesced hx order)
      int jj = o >> 4, m = o & 15;
      int op = m*4 + jj;
      float gi = gbuf[0*64 + op];
      float gf = gbuf[1*64 + op];
      float gu = gbuf[2*64 + op];
      float go = gbuf[3*64 + op];
      float cp = cbuf[op];
      float c = sigf(gf)*cp + sigf(gi)*tanhf(gu);
      float h = sigf(go)*tanhf(c);
      cbuf[op] = c;
      st_llc(&hx[(size_t)t*16384 + j0*16 + o], h);
      size_t oidx = ((size_t)(m*LL + t))*HH + j0 + jj;
      hs[oidx] = h;
      cs[oidx] = c;
      hs_bf[oidx] = f2bf(h);
    }
    if (t < LL-1)
      flagbar(flags, (unsigned)(t+1), ldsok);
  }
}

// ---------------------------------------------------------------------------
// Per-position rank-MLP score + gumbel noise (fp32 — decision path).
__global__ __launch_bounds__(128) void k_score(const float* __restrict__ R1t,
    const float* __restrict__ R2, const float* __restrict__ hs,
    const float* __restrict__ gumbel_u, float* __restrict__ score,
    float* __restrict__ snoisy){
  __shared__ float hsm[HH];
  __shared__ float red[128];
  int bt = blockIdx.x;
  int tid = threadIdx.x;
  for (int i = tid; i < HH; i += 128) hsm[i] = hs[(size_t)bt*HH + i];
  __syncthreads();
  float acc = 0.f;
  for (int k = 0; k < HH; ++k) acc += R1t[(size_t)k*RANKH + tid] * hsm[k];
  red[tid] = fmaxf(acc, 0.f) * R2[tid];
  __syncthreads();
  for (int s = 64; s > 0; s >>= 1){
    if (tid < s) red[tid] += red[tid+s];
    __syncthreads();
  }
  if (tid == 0){
    float s = red[0];
    float u = gumbel_u[bt];
    float noise = -logf(-logf(u));
    score[bt]  = s;
    snoisy[bt] = s + noise;
  }
}

// ---------------------------------------------------------------------------
// Build the tree structure for all batches. 1 block, 64 threads.
// level_count[0] <- number of levels (max height).
__global__ __launch_bounds__(64) void k_build(const float* __restrict__ score,
    const float* __restrict__ snoisy, const int* __restrict__ length,
    int* __restrict__ node_l, int* __restrict__ node_r, int* __restrict__ node_x,
    int* __restrict__ node_lvl, int* __restrict__ node_b, int* __restrict__ node_root,
    int* __restrict__ level_count, int* __restrict__ level_off, int* __restrict__ order){
  __shared__ float sc[BB*LL], sn[BB*LL];
  __shared__ int lcount[MAXLVL+1], lcur[MAXLVL+1], loff[MAXLVL+1];
  __shared__ int percnt[BB];
  int tid = threadIdx.x;
  for (int i = tid; i < BB*LL; i += 64){ sc[i] = score[i]; sn[i] = snoisy[i]; }
  for (int i = tid; i <= MAXLVL; i += 64){ lcount[i] = 0; lcur[i] = 0; }
  __syncthreads();
  if (tid < BB){
    int b = tid;
    int len = length[b];
    if (len > LL) len = LL;
    int qs[MAXN], qe[MAXN], qn[MAXN];
    int qh = 0, qt = 0, cnt = 0;
    int rootn = cnt++;
    qs[qt] = 0; qe[qt] = len; qn[qt] = rootn; qt++;
    while (qh < qt){
      int s0 = qs[qh], e0 = qe[qh], nid = qn[qh]; qh++;
      float best = sc[b*LL + s0]; int pos = s0;
      for (int t2 = s0+1; t2 < e0; ++t2){
        float v = sc[b*LL + t2];
        if (v > best){ best = v; pos = t2; }
      }
      float bestn = sn[b*LL + s0]; int js = s0;
      for (int t2 = s0+1; t2 < e0; ++t2){
        float v = sn[b*LL + t2];
        if (v > bestn){ bestn = v; js = t2; }
      }
      int gid = b*MAXN + nid;
      node_x[gid] = js;
      node_b[gid] = b;
      node_root[gid] = (nid == 0) ? 1 : 0;
      int ln = pos - s0, enc_l, enc_r;
      if (ln <= 0) enc_l = -1;
      else if (ln == 1) enc_l = 10000 + s0;
      else { int c2 = cnt++; enc_l = b*MAXN + c2; qs[qt]=s0; qe[qt]=pos; qn[qt]=c2; qt++; }
      int rn = e0 - (pos+1);
      if (rn <= 0) enc_r = -1;
      else if (rn == 1) enc_r = 10000 + (pos+1);
      else { int c2 = cnt++; enc_r = b*MAXN + c2; qs[qt]=pos+1; qe[qt]=e0; qn[qt]=c2; qt++; }
      node_l[gid] = enc_l; node_r[gid] = enc_r;
    }
    for (int i = cnt-1; i >= 0; --i){
      int gid = b*MAXN + i;
      int el = node_l[gid], er = node_r[gid];
      int llv = (el >= 0 && el < 10000) ? node_lvl[el] : 0;
      int rlv = (er >= 0 && er < 10000) ? node_lvl[er] : 0;
      node_lvl[gid] = 1 + (llv > rlv ? llv : rlv);
    }
    for (int i = 0; i < cnt; ++i) atomicAdd(&lcount[node_lvl[b*MAXN + i]], 1);
    percnt[b] = cnt;
  }
  __syncthreads();
  if (tid == 0){
    int off = 0, nlev = 0;
    for (int lv = 1; lv <= MAXLVL; ++lv){
      loff[lv] = off;
      level_off[lv] = off;
      level_count[lv] = lcount[lv];
      if (lcount[lv] > 0) nlev = lv;
      off += lcount[lv];
    }
    level_count[0] = nlev;
  }
  __syncthreads();
  if (tid < BB){
    int b = tid;
    int cnt = percnt[b];
    for (int i = 0; i < cnt; ++i){
      int gid = b*MAXN + i;
      int lv = node_lvl[gid];
      int p = atomicAdd(&lcur[lv], 1);
      order[loff[lv] + p] = gid;
    }
  }
}

// ---------------------------------------------------------------------------
// Persistent tree composition, distributed-flag barriers (R6-exact), NO wb/inv.
// Wc is LDS-RESIDENT: each of the 256 blocks owns 24 Wc rows (144KB, loaded
// once, XOR-swizzled). Per level every block computes its 24 gate columns for
// ALL nodes of the level; A-frags are L2-broadcast reads, B from LDS.
// Coherence protocol:
//  - gates: LLC stores (A) -> LLC loads (B)
//  - nodeH_bf / nodeC: LLC stores (B) -> normal cached first-reads later
//  - Wc_bf / hs_bf / order / node_*: read-only, cached.
__global__ __launch_bounds__(256, 1) void k_tree(
    const unsigned short* __restrict__ Wc_bf,
    const unsigned short* __restrict__ hs_bf,
    unsigned short* __restrict__ nodeH_bf,
    const unsigned short* __restrict__ zrow,
    const float* __restrict__ bc, const float* __restrict__ cs,
    float* __restrict__ nodeC,
    const int* __restrict__ node_l, const int* __restrict__ node_r,
    const int* __restrict__ node_x, const int* __restrict__ node_b,
    const int* __restrict__ node_root, const int* __restrict__ level_count,
    const int* __restrict__ level_off, const int* __restrict__ order,
    float* __restrict__ gates, float* __restrict__ out,
    unsigned* __restrict__ flags){
  __shared__ __align__(16) unsigned char wlds[24*6144];   // 144KB Wc slice
  __shared__ int ldsok[4];
  int tid = threadIdx.x;
  int lane = tid & 63;
  int wave = tid >> 6;
  int fr = lane & 15;          // fragment row (A: node slot, B: Wc row)
  int fkq = lane >> 4;         // k-quarter 0..3
  int fk  = fkq * 8;           // element offset within 32-elem k-chunk
  int fkb = fkq * 16;          // byte offset
  int swz = (fr & 7) << 4;     // XOR swizzle (G4: row-major stride-6144B tile)
  int base0 = fr * 6144;               // n-tile 0: rows 0..15
  int base1 = (16 + (fr & 7)) * 6144;  // n-tile 1: rows 16..23 (dup for fr>=8)
  int rg24 = blockIdx.x * 24;  // this block's 24 Wc rows / gate columns

  // ---- one-time: stage 24 Wc rows into LDS, swizzled ----
  for (int i = tid; i < 24*384; i += 256){
    int row = i / 384;
    int ch  = i - row*384;     // 16B chunk within row
    uint4 v = *(const uint4*)(Wc_bf + (size_t)(rg24 + row)*K3H + ch*8);
    *(uint4*)(wlds + row*6144 + ((ch*16) ^ ((row & 7) << 4))) = v;
  }
  __syncthreads();

  int nlev = level_count[0];
  unsigned ph = 0;
  for (int lvl = 1; lvl <= nlev; ++lvl){
    int n = level_count[lvl];
    int loffv = level_off[lvl];
    // ---- Phase A: all nodes x this block's 24 Wc rows, B from LDS ----
    int mtiles = (n + 15) >> 4;
    for (int mt = wave; mt < mtiles; mt += 4){
      int slot = mt*16 + fr;
      const unsigned short *pa0, *pa1, *pa2;
      if (slot < n){
        int gid = order[loffv + slot];
        int b = node_b[gid];
        int el = node_l[gid], er = node_r[gid], xt = node_x[gid];
        pa0 = (el < 0) ? zrow : (el >= 10000 ? hs_bf + (size_t)(b*LL + (el-10000))*HH
                                             : nodeH_bf + (size_t)el*HH);
        pa1 = (er < 0) ? zrow : (er >= 10000 ? hs_bf + (size_t)(b*LL + (er-10000))*HH
                                             : nodeH_bf + (size_t)er*HH);
        pa2 = hs_bf + (size_t)(b*LL + xt)*HH;
      } else { pa0 = zrow; pa1 = zrow; pa2 = zrow; }
      const unsigned short* pa[3] = {pa0, pa1, pa2};
      f32x4 acc0 = {0.f,0.f,0.f,0.f};
      f32x4 acc1 = {0.f,0.f,0.f,0.f};
      #pragma unroll
      for (int part = 0; part < 3; ++part){
        const unsigned short* ap = pa[part] + fk;
        #pragma unroll 8
        for (int kcc = 0; kcc < 1024; kcc += 32){
          bf16x8 a = *(const bf16x8*)(ap + kcc);
          int xb = part*2048 + kcc*2 + fkb;
          bf16x8 b0 = *(const bf16x8*)(wlds + base0 + (xb ^ swz));
          bf16x8 b1 = *(const bf16x8*)(wlds + base1 + (xb ^ swz));
          acc0 = __builtin_amdgcn_mfma_f32_16x16x32_bf16(a, b0, acc0, 0, 0, 0);
          acc1 = __builtin_amdgcn_mfma_f32_16x16x32_bf16(a, b1, acc1, 0, 0, 0);
        }
      }
      int m0 = mt*16 + fkq*4;
      #pragma unroll
      for (int r = 0; r < 4; ++r){
        int m = m0 + r;
        if (m < n){
          st_llc(&gates[(size_t)m*NG6 + rg24 + fr], acc0[r]);
          if (fr < 8)
            st_llc(&gates[(size_t)m*NG6 + rg24 + 16 + fr], acc1[r]);
        }
      }
    }
    ph++;
    flagbar(flags, ph, ldsok);
    // ---- Phase B: epilogue ----
    int items = n * 4;
    for (int it = blockIdx.x; it < items; it += 256){
      int ns = it >> 2;
      int j = (it & 3)*256 + tid;
      int gid = order[loffv + ns];
      int b = node_b[gid];
      int el = node_l[gid], er = node_r[gid], xt = node_x[gid];
      float gg[6];
      #pragma unroll
      for (int q = 0; q < 6; ++q)
        gg[q] = bc[q*HH + j] + ld_llc(&gates[(size_t)ns*NG6 + q*HH + j]);
      float lc = (el < 0) ? 0.f : (el >= 10000 ? cs[(size_t)(b*LL + (el-10000))*HH + j]
                                               : nodeC[(size_t)el*HH + j]);
      float rc = (er < 0) ? 0.f : (er >= 10000 ? cs[(size_t)(b*LL + (er-10000))*HH + j]
                                               : nodeC[(size_t)er*HH + j]);
      float xc = cs[(size_t)(b*LL + xt)*HH + j];
      float c = sigf(gg[0])*tanhf(gg[4]) + sigf(gg[1])*lc + sigf(gg[2])*rc + sigf(gg[3])*xc;
      float h = sigf(gg[5])*tanhf(c);
      st_llc_u16(&nodeH_bf[(size_t)gid*HH + j], (unsigned)f2bf(h));
      st_llc(&nodeC[(size_t)gid*HH + j], c);
      if (node_root[gid]){
        out[(size_t)b*HH + j] = h;
        out[(size_t)BB*HH + (size_t)b*HH + j] = c;
      }
    }
    if (lvl < nlev){
      ph++;
      flagbar(flags, ph, ldsok);
    }
  }
}

// ---------------------------------------------------------------------------
extern "C" void kernel_launch(void* const* d_in, const int* in_sizes, int n_in,
                              void* d_out, int out_size, void* d_ws, size_t ws_size,
                              hipStream_t stream){
  const float* se  = (const float*)d_in[0];
  const float* gu  = (const float*)d_in[1];
  const float* Wih = (const float*)d_in[2];
  const float* Whh = (const float*)d_in[3];
  const float* bih = (const float*)d_in[4];
  const float* bhh = (const float*)d_in[5];
  const float* R1  = (const float*)d_in[6];
  const float* R2  = (const float*)d_in[7];
  const float* Wc  = (const float*)d_in[8];
  const float* bc  = (const float*)d_in[9];
  const int*   len = (const int*)d_in[10];
  float* out = (float*)d_out;                 // [2,16,1024] fp32

  float* ws = (float*)d_ws;
  size_t off = 0;
  float* R1t   = ws + off; off += (size_t)HH*RANKH;
  float* Gx    = ws + off; off += (size_t)BB*LL*NG4;     // [m][t][4096]
  float* Gxt   = ws + off; off += (size_t)BB*LL*NG4;     // [t][4096][m]
  float* hx    = ws + off; off += (size_t)LL*HH*BB;      // [t][j][m] exchange (3MB)
  float* hs    = ws + off; off += (size_t)BB*LL*HH;
  float* cs    = ws + off; off += (size_t)BB*LL*HH;
  float* nodeC = ws + off; off += (size_t)TOTN*HH;
  float* gates = ws + off; off += (size_t)MAXNPL*NG6;
  unsigned short* Wc_bf    = (unsigned short*)(ws + off); off += (size_t)NG6*K3H/2;
  unsigned short* hs_bf    = (unsigned short*)(ws + off); off += (size_t)BB*LL*HH/2;
  unsigned short* nodeH_bf = (unsigned short*)(ws + off); off += (size_t)TOTN*HH/2 + 512;
  unsigned short* zrow     = (unsigned short*)(ws + off); off += 512;  // 1024 zero bf16
  float* score = ws + off; off += 1024;
  float* snoi  = ws + off; off += 1024;
  unsigned* flags = (unsigned*)(ws + off); off += 2*FDOM; // scan @0, tree @ +FDOM dwords
  int* ib = (int*)(ws + off);
  int* node_l    = ib; ib += 768;
  int* node_r    = ib; ib += 768;
  int* node_x    = ib; ib += 768;
  int* node_lvl  = ib; ib += 768;
  int* node_b    = ib; ib += 768;
  int* node_root = ib; ib += 768;
  int* level_count = ib; ib += 64;
  int* level_off   = ib; ib += 64;
  int* order       = ib; ib += 768;

  // hi/lo bf16 split scratch OVERLAID on Wc_bf (k_cvt for Wc runs AFTER the
  // GEMM, stream-ordered, so the region is free during the split/GEMM phase):
  // seh/sel: 768x1024, wih_h/wih_l: 4096x1024 -> 9.96M ushorts < 18.9M avail.
  unsigned short* seh   = Wc_bf;
  unsigned short* sel   = Wc_bf + 786432;
  unsigned short* wih_h = Wc_bf + 2*786432;
  unsigned short* wih_l = Wc_bf + 2*786432 + 4194304;

  // 0. zero flag arrays + dummy zero row (ws poisoned every launch)
  k_init<<<1, 256, 0, stream>>>(flags, zrow);
  // 1. R1 transpose
  k_transpose<<<dim3(32, 4), dim3(32, 8), 0, stream>>>(R1, R1t, RANKH, HH);
  // 2. hi/lo split of se and Wih, then input-side gate GEMM via MFMA
  k_split<<<768, 256, 0, stream>>>(se, seh, sel, 786432);
  k_split<<<4096, 256, 0, stream>>>(Wih, wih_h, wih_l, 4194304);
  k_gemm_gx_mfma<<<dim3(12, 64), 256, 0, stream>>>(seh, sel, wih_h, wih_l,
                                                   bih, bhh, Gx);
  k_gx_t<<<dim3(48, 16), 256, 0, stream>>>(Gx, Gxt);
  // 3. Wc bf16 conversion (overwrites the split scratch — safe, GEMM done)
  k_cvt_bf16<<<(NG6*K3H)/1024, 256, 0, stream>>>(Wc, Wc_bf, NG6*K3H);
  // 4. persistent recurrent LSTM scan (48 steps, flag barriers, R6-exact)
  k_lstm_scan<<<256, 256, 0, stream>>>(Whh, Gxt, hx, hs, cs, hs_bf, flags);
  // 5. per-position scores + gumbel noise (fp32)
  k_score<<<BB*LL, 128, 0, stream>>>(R1t, R2, hs, gu, score, snoi);
  // 6. tree structure
  k_build<<<1, 64, 0, stream>>>(score, snoi, len, node_l, node_r, node_x,
                                node_lvl, node_b, node_root,
                                level_count, level_off, order);
  // 7. persistent level-by-level nary composition (flag barriers, R6-exact)
  k_tree<<<256, 256, 0, stream>>>(Wc_bf, hs_bf, nodeH_bf, zrow, bc, cs, nodeC,
                                  node_l, node_r, node_x, node_b, node_root,
                                  level_count, level_off, order,
                                  gates, out, flags + FDOM);
}

// Round 11
// 1035.317 us; speedup vs baseline: 1.1601x; 1.0363x over previous
//
#include <hip/hip_runtime.h>
#include <math.h>

#define BB 16
#define LL 48
#define HH 1024
#define NG4 4096      // 4*H
#define NG6 6144      // 6*H
#define K3H 3072      // 3*H
#define RANKH 128
#define MAXN 47       // max nodes per batch (len-1 <= 47)
#define TOTN (BB*MAXN)
#define MAXLVL 48
#define MAXNPL 384    // max nodes in one level

#define FSTRIDE 32    // dwords between flag lines (128B line spacing)
#define FDOM 8192     // dwords per barrier domain (scan @0, tree @FDOM)
#define HS_S 1028     // padded LDS row stride (floats) for h-stage

typedef __attribute__((ext_vector_type(8))) short bf16x8;
typedef __attribute__((ext_vector_type(4))) float f32x4;

__device__ __forceinline__ float sigf(float x){ return 1.f/(1.f + expf(-x)); }

__device__ __forceinline__ unsigned short f2bf(float f){
  union { float f; unsigned u; } v; v.f = f;
  unsigned r = v.u + 0x7fff + ((v.u >> 16) & 1);
  return (unsigned short)(r >> 16);
}

// ---- LLC-coherent ops (device coherence point; bypass L1/L2, no allocate) ----
__device__ __forceinline__ void st_llc(float* p, float v){
  __hip_atomic_store(p, v, __ATOMIC_RELAXED, __HIP_MEMORY_SCOPE_AGENT);
}
__device__ __forceinline__ float ld_llc(const float* p){
  return __hip_atomic_load(p, __ATOMIC_RELAXED, __HIP_MEMORY_SCOPE_AGENT);
}
__device__ __forceinline__ void st_llc_u16(unsigned short* p, unsigned v){
  asm volatile("global_store_short %0, %1, off sc0 sc1" :: "v"(p), "v"(v) : "memory");
}
__device__ __forceinline__ void st_llc_u32(unsigned* p, unsigned v){
  asm volatile("global_store_dword %0, %1, off sc0 sc1" :: "v"(p), "v"(v) : "memory");
}
__device__ __forceinline__ void wait_vm0(){
  asm volatile("s_waitcnt vmcnt(0)" ::: "memory");
}

// Distributed-flag grid barrier, HOT-SPIN variant. (Flag-store barriers are
// the only mechanism that has passed correctness on this part; atomic-RMW
// barriers corrupted twice and are condemned; per-step kernel launches cost
// ~10us each and lost.) Each block owns a PRIVATE 128B line; arrival stores
// land in parallel across LLC banks. Poll: each WAVE independently hot-spins
// on its own 64 lines (load + vmcnt + __all; NO sleep, NO LDS reduce, NO
// per-iteration syncthreads — R4/R5 proved poll volume is harmless, so make
// iterations cheap instead of rare), then one __syncthreads joins the 4
// waves: monotonic flags => when the join passes, all 256 flags were seen
// >= p. Data crossing the barrier must use LLC ops (st_llc*) or be
// first-read-after-write. flags MUST be zeroed every launch.
__device__ __forceinline__ void flagbar(unsigned* flags, unsigned p){
  wait_vm0();
  __syncthreads();
  int tid = threadIdx.x;
  if (tid == 0)
    st_llc_u32(&flags[blockIdx.x*FSTRIDE], p);
  for (;;){
    unsigned v;
    asm volatile("global_load_dword %0, %1, off sc0 sc1"
                 : "=v"(v) : "v"(&flags[tid*FSTRIDE]));
    wait_vm0();
    if (__all((int)(v >= p))) break;
  }
  __syncthreads();
}

// ---------------------------------------------------------------------------
// Zero both flag domains + the zero dummy row.
__global__ __launch_bounds__(256) void k_init(unsigned* flags, unsigned short* zrow){
  int tid = threadIdx.x;
  for (int i = tid; i < 2*FDOM; i += 256) flags[i] = 0u;
  for (int i = tid; i < 1024; i += 256) zrow[i] = 0;
}

// ---------------------------------------------------------------------------
// fp32 -> bf16 (RNE), vectorized. n multiple of 1024.
__global__ __launch_bounds__(256) void k_cvt_bf16(const float* __restrict__ in,
    unsigned short* __restrict__ out, int n){
  int i = (blockIdx.x*256 + threadIdx.x)*4;
  if (i >= n) return;
  float4 v = *(const float4*)(in + i);
  ushort4 o;
  o.x = f2bf(v.x); o.y = f2bf(v.y); o.z = f2bf(v.z); o.w = f2bf(v.w);
  *(ushort4*)(out + i) = o;
}

// ---------------------------------------------------------------------------
// Generic 32x32 LDS-tiled transpose: out[C][R] = in[R][C]^T  (R1 only)
__global__ __launch_bounds__(256) void k_transpose(const float* __restrict__ in,
                                                   float* __restrict__ out, int R, int C){
  __shared__ float t[32][33];
  int bx = blockIdx.x*32, by = blockIdx.y*32;
  int x = threadIdx.x, y = threadIdx.y;   // block (32,8)
  #pragma unroll
  for (int i = 0; i < 32; i += 8){
    int r = by + y + i, c = bx + x;
    if (r < R && c < C) t[y+i][x] = in[(size_t)r*C + c];
  }
  __syncthreads();
  #pragma unroll
  for (int i = 0; i < 32; i += 8){
    int r = bx + y + i, c = by + x;       // out dims [C][R]
    if (r < C && c < R) out[(size_t)r*R + c] = t[x][y+i];
  }
}

// ---------------------------------------------------------------------------
// Gx[m][n] = sum_k se[m][k]*Wih[n][k] + bih[n] + bhh[n]   (fp32 — decision path)
__global__ __launch_bounds__(256) void k_gemm_gx(const float* __restrict__ A,
    const float* __restrict__ Bw, const float* __restrict__ bih,
    const float* __restrict__ bhh, float* __restrict__ Cout, int M, int N, int K){
  __shared__ float as[16][68];
  __shared__ float bs[16][68];
  int m0 = blockIdx.x*64, n0 = blockIdx.y*64;
  int tid = threadIdx.x;
  int mt = tid & 15, nt = tid >> 4;
  float acc[4][4] = {};
  for (int k0 = 0; k0 < K; k0 += 16){
    #pragma unroll
    for (int it = 0; it < 4; ++it){
      int idx = it*256 + tid;
      int kk = idx & 15, mm = idx >> 4;
      as[kk][mm] = A[(size_t)(m0+mm)*K + k0 + kk];
      bs[kk][mm] = Bw[(size_t)(n0+mm)*K + k0 + kk];
    }
    __syncthreads();
    #pragma unroll
    for (int kk = 0; kk < 16; ++kk){
      float a4[4], b4[4];
      #pragma unroll
      for (int i = 0; i < 4; ++i) a4[i] = as[kk][mt*4+i];
      #pragma unroll
      for (int i = 0; i < 4; ++i) b4[i] = bs[kk][nt*4+i];
      #pragma unroll
      for (int i = 0; i < 4; ++i)
        #pragma unroll
        for (int j2 = 0; j2 < 4; ++j2) acc[i][j2] += a4[i]*b4[j2];
    }
    __syncthreads();
  }
  #pragma unroll
  for (int i = 0; i < 4; ++i){
    int m = m0 + mt*4 + i;
    #pragma unroll
    for (int j2 = 0; j2 < 4; ++j2){
      int n = n0 + nt*4 + j2;
      Cout[(size_t)m*N + n] = acc[i][j2] + bih[n] + bhh[n];
    }
  }
}

// ---------------------------------------------------------------------------
// Gx [m][t][4096] -> Gxt [t][4096][m]  (for coalesced per-step gate reads)
__global__ __launch_bounds__(256) void k_gx_t(const float* __restrict__ Gx,
                                              float* __restrict__ Gxt){
  __shared__ float t2[16][257];
  int t = blockIdx.x;       // 48
  int rc = blockIdx.y;      // 16 chunks of 256 rows
  int tid = threadIdx.x;
  #pragma unroll
  for (int m = 0; m < 16; ++m)
    t2[m][tid] = Gx[((size_t)(m*48 + t))*4096 + rc*256 + tid];
  __syncthreads();
  int rl = tid >> 4, m = tid & 15;
  #pragma unroll
  for (int i = 0; i < 16; ++i){
    int r = rc*256 + i*16 + rl;
    Gxt[((size_t)t*4096 + r)*16 + m] = t2[m][i*16 + rl];
  }
}

// ---------------------------------------------------------------------------
// Persistent LSTM scan: 256 blocks x 256 threads, 1 block/CU. (R6 structure:
// best measured passing config.) Cross-step h via hx[t][j][m]: producer tail
// writes ONE contiguous 256B st_llc burst; consumers read the 64KB slab with
// contiguous cached dwordx4 (first-read-after-write -> fresh LLC lines,
// L2-shared per XCD), then LDS-transpose [j][m]->[m][j]. hs/cs/hs_bf are
// consumed by later kernels only -> plain cached stores. Whh registers
// PERMUTED to the [m][k] layout:
//   lane kc owns k-indices {r*256 + 4*kc + j : r=0..3, j=0..3}
__global__ __launch_bounds__(256, 1) void k_lstm_scan(
    const float* __restrict__ Whh, const float* __restrict__ Gxt,
    float* __restrict__ hx,
    float* __restrict__ hs, float* __restrict__ cs,
    unsigned short* __restrict__ hs_bf, unsigned* __restrict__ flags){
  __shared__ float smem[17408];   // 68KB: h-stage [16][HS_S]; overlaid by reduce partials
  __shared__ float gbuf[4*64];
  __shared__ float cbuf[64];
  int tid = threadIdx.x;
  int g = tid >> 6, kc = tid & 63;
  int j0 = blockIdx.x * 4;
  float w[4][16];
  #pragma unroll
  for (int jj = 0; jj < 4; ++jj){
    const float* src = Whh + (size_t)(g*1024 + j0 + jj)*1024 + kc*4;
    #pragma unroll
    for (int r = 0; r < 4; ++r){
      float4 v = *(const float4*)(src + r*256);
      w[jj][r*4+0]=v.x; w[jj][r*4+1]=v.y; w[jj][r*4+2]=v.z; w[jj][r*4+3]=v.w;
    }
  }
  if (tid < 64) cbuf[tid] = 0.f;
  for (int t = 0; t < LL; ++t){
    float gx = Gxt[((size_t)t*NG4 + g*1024 + j0 + (kc & 3))*16 + (kc >> 2)];
    float G = 0.f;
    if (t > 0){
      const float* slab = hx + (size_t)(t-1)*16384;
      f32x4 hv[16];
      #pragma unroll
      for (int i = 0; i < 16; ++i)
        hv[i] = *(const f32x4*)(slab + i*1024 + tid*4);
      {
        int mb = (tid & 3) * 4;
        int jb = tid >> 2;
        #pragma unroll
        for (int i = 0; i < 16; ++i){
          #pragma unroll
          for (int e = 0; e < 4; ++e)
            smem[(size_t)(mb + e)*HS_S + i*64 + jb] = hv[i][e];
        }
      }
      __syncthreads();
      float acc[4][16];
      #pragma unroll 4
      for (int m = 0; m < 16; ++m){
        const float* hb = &smem[(size_t)m*HS_S + (kc<<2)];
        float4 h0 = *(const float4*)(hb);
        float4 h1 = *(const float4*)(hb+256);
        float4 h2 = *(const float4*)(hb+512);
        float4 h3 = *(const float4*)(hb+768);
        #pragma unroll
        for (int jj = 0; jj < 4; ++jj){
          float s = w[jj][0]*h0.x + w[jj][1]*h0.y + w[jj][2]*h0.z + w[jj][3]*h0.w
                  + w[jj][4]*h1.x + w[jj][5]*h1.y + w[jj][6]*h1.z + w[jj][7]*h1.w
                  + w[jj][8]*h2.x + w[jj][9]*h2.y + w[jj][10]*h2.z + w[jj][11]*h2.w
                  + w[jj][12]*h3.x + w[jj][13]*h3.y + w[jj][14]*h3.z + w[jj][15]*h3.w;
          acc[jj][m] = s;
        }
      }
      __syncthreads();   // h reads done; smem reused as reduce partials
      #pragma unroll
      for (int m = 0; m < 16; ++m){
        float4 v;
        v.x = acc[0][m]; v.y = acc[1][m]; v.z = acc[2][m]; v.w = acc[3][m];
        *(float4*)&smem[(size_t)(g*64 + kc)*68 + m*4] = v;
      }
      __syncthreads();
      {
        float s0=0.f,s1=0.f,s2=0.f,s3=0.f;
        #pragma unroll 4
        for (int l = 0; l < 64; l += 4){
          s0 += smem[(size_t)(g*64 + l  )*68 + kc];
          s1 += smem[(size_t)(g*64 + l+1)*68 + kc];
          s2 += smem[(size_t)(g*64 + l+2)*68 + kc];
          s3 += smem[(size_t)(g*64 + l+3)*68 + kc];
        }
        G = (s0+s1)+(s2+s3);
      }
    }
    gbuf[g*64 + kc] = G + gx;
    __syncthreads();
    if (g == 0){
      int o = kc;                       // o = jj*16 + m (coalesced hx order)
      int jj = o >> 4, m = o & 15;
      int op = m*4 + jj;
      float gi = gbuf[0*64 + op];
      float gf = gbuf[1*64 + op];
      float gu = gbuf[2*64 + op];
      float go = gbuf[3*64 + op];
      float cp = cbuf[op];
      float c = sigf(gf)*cp + sigf(gi)*tanhf(gu);
      float h = sigf(go)*tanhf(c);
      cbuf[op] = c;
      st_llc(&hx[(size_t)t*16384 + j0*16 + o], h);
      size_t oidx = ((size_t)(m*LL + t))*HH + j0 + jj;
      hs[oidx] = h;
      cs[oidx] = c;
      hs_bf[oidx] = f2bf(h);
    }
    if (t < LL-1)
      flagbar(flags, (unsigned)(t+1));
  }
}

// ---------------------------------------------------------------------------
// Per-position rank-MLP score + gumbel noise (fp32 — decision path).
__global__ __launch_bounds__(128) void k_score(const float* __restrict__ R1t,
    const float* __restrict__ R2, const float* __restrict__ hs,
    const float* __restrict__ gumbel_u, float* __restrict__ score,
    float* __restrict__ snoisy){
  __shared__ float hsm[HH];
  __shared__ float red[128];
  int bt = blockIdx.x;
  int tid = threadIdx.x;
  for (int i = tid; i < HH; i += 128) hsm[i] = hs[(size_t)bt*HH + i];
  __syncthreads();
  float acc = 0.f;
  for (int k = 0; k < HH; ++k) acc += R1t[(size_t)k*RANKH + tid] * hsm[k];
  red[tid] = fmaxf(acc, 0.f) * R2[tid];
  __syncthreads();
  for (int s = 64; s > 0; s >>= 1){
    if (tid < s) red[tid] += red[tid+s];
    __syncthreads();
  }
  if (tid == 0){
    float s = red[0];
    float u = gumbel_u[bt];
    float noise = -logf(-logf(u));
    score[bt]  = s;
    snoisy[bt] = s + noise;
  }
}

// ---------------------------------------------------------------------------
// Build the tree structure for all batches. 1 block, 64 threads.
// level_count[0] <- number of levels (max height).
__global__ __launch_bounds__(64) void k_build(const float* __restrict__ score,
    const float* __restrict__ snoisy, const int* __restrict__ length,
    int* __restrict__ node_l, int* __restrict__ node_r, int* __restrict__ node_x,
    int* __restrict__ node_lvl, int* __restrict__ node_b, int* __restrict__ node_root,
    int* __restrict__ level_count, int* __restrict__ level_off, int* __restrict__ order){
  __shared__ float sc[BB*LL], sn[BB*LL];
  __shared__ int lcount[MAXLVL+1], lcur[MAXLVL+1], loff[MAXLVL+1];
  __shared__ int percnt[BB];
  int tid = threadIdx.x;
  for (int i = tid; i < BB*LL; i += 64){ sc[i] = score[i]; sn[i] = snoisy[i]; }
  for (int i = tid; i <= MAXLVL; i += 64){ lcount[i] = 0; lcur[i] = 0; }
  __syncthreads();
  if (tid < BB){
    int b = tid;
    int len = length[b];
    if (len > LL) len = LL;
    int qs[MAXN], qe[MAXN], qn[MAXN];
    int qh = 0, qt = 0, cnt = 0;
    int rootn = cnt++;
    qs[qt] = 0; qe[qt] = len; qn[qt] = rootn; qt++;
    while (qh < qt){
      int s0 = qs[qh], e0 = qe[qh], nid = qn[qh]; qh++;
      float best = sc[b*LL + s0]; int pos = s0;
      for (int t2 = s0+1; t2 < e0; ++t2){
        float v = sc[b*LL + t2];
        if (v > best){ best = v; pos = t2; }
      }
      float bestn = sn[b*LL + s0]; int js = s0;
      for (int t2 = s0+1; t2 < e0; ++t2){
        float v = sn[b*LL + t2];
        if (v > bestn){ bestn = v; js = t2; }
      }
      int gid = b*MAXN + nid;
      node_x[gid] = js;
      node_b[gid] = b;
      node_root[gid] = (nid == 0) ? 1 : 0;
      int ln = pos - s0, enc_l, enc_r;
      if (ln <= 0) enc_l = -1;
      else if (ln == 1) enc_l = 10000 + s0;
      else { int c2 = cnt++; enc_l = b*MAXN + c2; qs[qt]=s0; qe[qt]=pos; qn[qt]=c2; qt++; }
      int rn = e0 - (pos+1);
      if (rn <= 0) enc_r = -1;
      else if (rn == 1) enc_r = 10000 + (pos+1);
      else { int c2 = cnt++; enc_r = b*MAXN + c2; qs[qt]=pos+1; qe[qt]=e0; qn[qt]=c2; qt++; }
      node_l[gid] = enc_l; node_r[gid] = enc_r;
    }
    for (int i = cnt-1; i >= 0; --i){
      int gid = b*MAXN + i;
      int el = node_l[gid], er = node_r[gid];
      int llv = (el >= 0 && el < 10000) ? node_lvl[el] : 0;
      int rlv = (er >= 0 && er < 10000) ? node_lvl[er] : 0;
      node_lvl[gid] = 1 + (llv > rlv ? llv : rlv);
    }
    for (int i = 0; i < cnt; ++i) atomicAdd(&lcount[node_lvl[b*MAXN + i]], 1);
    percnt[b] = cnt;
  }
  __syncthreads();
  if (tid == 0){
    int off = 0, nlev = 0;
    for (int lv = 1; lv <= MAXLVL; ++lv){
      loff[lv] = off;
      level_off[lv] = off;
      level_count[lv] = lcount[lv];
      if (lcount[lv] > 0) nlev = lv;
      off += lcount[lv];
    }
    level_count[0] = nlev;
  }
  __syncthreads();
  if (tid < BB){
    int b = tid;
    int cnt = percnt[b];
    for (int i = 0; i < cnt; ++i){
      int gid = b*MAXN + i;
      int lv = node_lvl[gid];
      int p = atomicAdd(&lcur[lv], 1);
      order[loff[lv] + p] = gid;
    }
  }
}

// ---------------------------------------------------------------------------
// Persistent tree composition, hot-spin flag barriers, NO wb/inv.
// Wc is LDS-RESIDENT: each of the 256 blocks owns 24 Wc rows (144KB, loaded
// once, XOR-swizzled). Per level every block computes its 24 gate columns for
// ALL nodes of the level; A-frags are L2-broadcast reads, B from LDS.
// Coherence protocol:
//  - gates: LLC stores (A) -> LLC loads (B)
//  - nodeH_bf / nodeC: LLC stores (B) -> normal cached first-reads later
//  - Wc_bf / hs_bf / order / node_*: read-only, cached.
__global__ __launch_bounds__(256, 1) void k_tree(
    const unsigned short* __restrict__ Wc_bf,
    const unsigned short* __restrict__ hs_bf,
    unsigned short* __restrict__ nodeH_bf,
    const unsigned short* __restrict__ zrow,
    const float* __restrict__ bc, const float* __restrict__ cs,
    float* __restrict__ nodeC,
    const int* __restrict__ node_l, const int* __restrict__ node_r,
    const int* __restrict__ node_x, const int* __restrict__ node_b,
    const int* __restrict__ node_root, const int* __restrict__ level_count,
    const int* __restrict__ level_off, const int* __restrict__ order,
    float* __restrict__ gates, float* __restrict__ out,
    unsigned* __restrict__ flags){
  __shared__ __align__(16) unsigned char wlds[24*6144];   // 144KB Wc slice
  int tid = threadIdx.x;
  int lane = tid & 63;
  int wave = tid >> 6;
  int fr = lane & 15;          // fragment row (A: node slot, B: Wc row)
  int fkq = lane >> 4;         // k-quarter 0..3
  int fk  = fkq * 8;           // element offset within 32-elem k-chunk
  int fkb = fkq * 16;          // byte offset
  int swz = (fr & 7) << 4;     // XOR swizzle (G4: row-major stride-6144B tile)
  int base0 = fr * 6144;               // n-tile 0: rows 0..15
  int base1 = (16 + (fr & 7)) * 6144;  // n-tile 1: rows 16..23 (dup for fr>=8)
  int rg24 = blockIdx.x * 24;  // this block's 24 Wc rows / gate columns

  // ---- one-time: stage 24 Wc rows into LDS, swizzled ----
  for (int i = tid; i < 24*384; i += 256){
    int row = i / 384;
    int ch  = i - row*384;     // 16B chunk within row
    uint4 v = *(const uint4*)(Wc_bf + (size_t)(rg24 + row)*K3H + ch*8);
    *(uint4*)(wlds + row*6144 + ((ch*16) ^ ((row & 7) << 4))) = v;
  }
  __syncthreads();

  int nlev = level_count[0];
  unsigned ph = 0;
  for (int lvl = 1; lvl <= nlev; ++lvl){
    int n = level_count[lvl];
    int loffv = level_off[lvl];
    // ---- Phase A: all nodes x this block's 24 Wc rows, B from LDS ----
    int mtiles = (n + 15) >> 4;
    for (int mt = wave; mt < mtiles; mt += 4){
      int slot = mt*16 + fr;
      const unsigned short *pa0, *pa1, *pa2;
      if (slot < n){
        int gid = order[loffv + slot];
        int b = node_b[gid];
        int el = node_l[gid], er = node_r[gid], xt = node_x[gid];
        pa0 = (el < 0) ? zrow : (el >= 10000 ? hs_bf + (size_t)(b*LL + (el-10000))*HH
                                             : nodeH_bf + (size_t)el*HH);
        pa1 = (er < 0) ? zrow : (er >= 10000 ? hs_bf + (size_t)(b*LL + (er-10000))*HH
                                             : nodeH_bf + (size_t)er*HH);
        pa2 = hs_bf + (size_t)(b*LL + xt)*HH;
      } else { pa0 = zrow; pa1 = zrow; pa2 = zrow; }
      const unsigned short* pa[3] = {pa0, pa1, pa2};
      f32x4 acc0 = {0.f,0.f,0.f,0.f};
      f32x4 acc1 = {0.f,0.f,0.f,0.f};
      #pragma unroll
      for (int part = 0; part < 3; ++part){
        const unsigned short* ap = pa[part] + fk;
        #pragma unroll 8
        for (int kcc = 0; kcc < 1024; kcc += 32){
          bf16x8 a = *(const bf16x8*)(ap + kcc);
          int xb = part*2048 + kcc*2 + fkb;
          bf16x8 b0 = *(const bf16x8*)(wlds + base0 + (xb ^ swz));
          bf16x8 b1 = *(const bf16x8*)(wlds + base1 + (xb ^ swz));
          acc0 = __builtin_amdgcn_mfma_f32_16x16x32_bf16(a, b0, acc0, 0, 0, 0);
          acc1 = __builtin_amdgcn_mfma_f32_16x16x32_bf16(a, b1, acc1, 0, 0, 0);
        }
      }
      int m0 = mt*16 + fkq*4;
      #pragma unroll
      for (int r = 0; r < 4; ++r){
        int m = m0 + r;
        if (m < n){
          st_llc(&gates[(size_t)m*NG6 + rg24 + fr], acc0[r]);
          if (fr < 8)
            st_llc(&gates[(size_t)m*NG6 + rg24 + 16 + fr], acc1[r]);
        }
      }
    }
    ph++;
    flagbar(flags, ph);
    // ---- Phase B: epilogue ----
    int items = n * 4;
    for (int it = blockIdx.x; it < items; it += 256){
      int ns = it >> 2;
      int j = (it & 3)*256 + tid;
      int gid = order[loffv + ns];
      int b = node_b[gid];
      int el = node_l[gid], er = node_r[gid], xt = node_x[gid];
      float gg[6];
      #pragma unroll
      for (int q = 0; q < 6; ++q)
        gg[q] = bc[q*HH + j] + ld_llc(&gates[(size_t)ns*NG6 + q*HH + j]);
      float lc = (el < 0) ? 0.f : (el >= 10000 ? cs[(size_t)(b*LL + (el-10000))*HH + j]
                                               : nodeC[(size_t)el*HH + j]);
      float rc = (er < 0) ? 0.f : (er >= 10000 ? cs[(size_t)(b*LL + (er-10000))*HH + j]
                                               : nodeC[(size_t)er*HH + j]);
      float xc = cs[(size_t)(b*LL + xt)*HH + j];
      float c = sigf(gg[0])*tanhf(gg[4]) + sigf(gg[1])*lc + sigf(gg[2])*rc + sigf(gg[3])*xc;
      float h = sigf(gg[5])*tanhf(c);
      st_llc_u16(&nodeH_bf[(size_t)gid*HH + j], (unsigned)f2bf(h));
      st_llc(&nodeC[(size_t)gid*HH + j], c);
      if (node_root[gid]){
        out[(size_t)b*HH + j] = h;
        out[(size_t)BB*HH + (size_t)b*HH + j] = c;
      }
    }
    if (lvl < nlev){
      ph++;
      flagbar(flags, ph);
    }
  }
}

// ---------------------------------------------------------------------------
extern "C" void kernel_launch(void* const* d_in, const int* in_sizes, int n_in,
                              void* d_out, int out_size, void* d_ws, size_t ws_size,
                              hipStream_t stream){
  const float* se  = (const float*)d_in[0];
  const float* gu  = (const float*)d_in[1];
  const float* Wih = (const float*)d_in[2];
  const float* Whh = (const float*)d_in[3];
  const float* bih = (const float*)d_in[4];
  const float* bhh = (const float*)d_in[5];
  const float* R1  = (const float*)d_in[6];
  const float* R2  = (const float*)d_in[7];
  const float* Wc  = (const float*)d_in[8];
  const float* bc  = (const float*)d_in[9];
  const int*   len = (const int*)d_in[10];
  float* out = (float*)d_out;                 // [2,16,1024] fp32

  float* ws = (float*)d_ws;
  size_t off = 0;
  float* R1t   = ws + off; off += (size_t)HH*RANKH;
  float* Gx    = ws + off; off += (size_t)BB*LL*NG4;     // [m][t][4096]
  float* Gxt   = ws + off; off += (size_t)BB*LL*NG4;     // [t][4096][m]
  float* hx    = ws + off; off += (size_t)LL*HH*BB;      // [t][j][m] exchange (3MB)
  float* hs    = ws + off; off += (size_t)BB*LL*HH;
  float* cs    = ws + off; off += (size_t)BB*LL*HH;
  float* nodeC = ws + off; off += (size_t)TOTN*HH;
  float* gates = ws + off; off += (size_t)MAXNPL*NG6;
  unsigned short* Wc_bf    = (unsigned short*)(ws + off); off += (size_t)NG6*K3H/2;
  unsigned short* hs_bf    = (unsigned short*)(ws + off); off += (size_t)BB*LL*HH/2;
  unsigned short* nodeH_bf = (unsigned short*)(ws + off); off += (size_t)TOTN*HH/2 + 512;
  unsigned short* zrow     = (unsigned short*)(ws + off); off += 512;  // 1024 zero bf16
  float* score = ws + off; off += 1024;
  float* snoi  = ws + off; off += 1024;
  unsigned* flags = (unsigned*)(ws + off); off += 2*FDOM; // scan @0, tree @ +FDOM dwords
  int* ib = (int*)(ws + off);
  int* node_l    = ib; ib += 768;
  int* node_r    = ib; ib += 768;
  int* node_x    = ib; ib += 768;
  int* node_lvl  = ib; ib += 768;
  int* node_b    = ib; ib += 768;
  int* node_root = ib; ib += 768;
  int* level_count = ib; ib += 64;
  int* level_off   = ib; ib += 64;
  int* order       = ib; ib += 768;

  // 0. zero flag arrays + dummy zero row (ws poisoned every launch)
  k_init<<<1, 256, 0, stream>>>(flags, zrow);
  // 1. R1 transpose + Wc bf16 conversion
  k_transpose<<<dim3(32, 4), dim3(32, 8), 0, stream>>>(R1, R1t, RANKH, HH);
  k_cvt_bf16<<<(NG6*K3H)/1024, 256, 0, stream>>>(Wc, Wc_bf, NG6*K3H);
  // 2. input-side gate GEMM (+ both biases), then transpose for the scan
  k_gemm_gx<<<dim3(12, 64), 256, 0, stream>>>(se, Wih, bih, bhh, Gx, BB*LL, NG4, HH);
  k_gx_t<<<dim3(48, 16), 256, 0, stream>>>(Gx, Gxt);
  // 3. persistent recurrent LSTM scan (48 steps, hot-spin flag barriers)
  k_lstm_scan<<<256, 256, 0, stream>>>(Whh, Gxt, hx, hs, cs, hs_bf, flags);
  // 4. per-position scores + gumbel noise (fp32)
  k_score<<<BB*LL, 128, 0, stream>>>(R1t, R2, hs, gu, score, snoi);
  // 5. tree structure
  k_build<<<1, 64, 0, stream>>>(score, snoi, len, node_l, node_r, node_x,
                                node_lvl, node_b, node_root,
                                level_count, level_off, order);
  // 6. persistent level-by-level nary composition (hot-spin flag barriers)
  k_tree<<<256, 256, 0, stream>>>(Wc_bf, hs_bf, nodeH_bf, zrow, bc, cs, nodeC,
                                  node_l, node_r, node_x, node_b, node_root,
                                  level_count, level_off, order,
                                  gates, out, flags + FDOM);
}

// Round 12
// 1019.733 us; speedup vs baseline: 1.1778x; 1.0153x over previous
//
#include <hip/hip_runtime.h>
#include <math.h>

#define BB 16
#define LL 48
#define HH 1024
#define NG4 4096      // 4*H
#define NG6 6144      // 6*H
#define K3H 3072      // 3*H
#define RANKH 128
#define MAXN 47       // max nodes per batch (len-1 <= 47)
#define TOTN (BB*MAXN)
#define MAXLVL 48
#define MAXNPL 384    // max nodes in one level

#define FSTRIDE 32    // dwords between flag lines (128B line spacing)
#define FDOM 8192     // dwords per barrier domain (scan @0, tree @FDOM)
#define HS_S 1028     // padded LDS row stride (floats) for h-stage
#define RED_S 65      // reduce-partial stride (floats): bank-step 1 = conflict-free

#define NB_CVT 18432  // (NG6*K3H)/1024 blocks for the Wc cvt branch of k_pre

typedef __attribute__((ext_vector_type(8))) short bf16x8;
typedef __attribute__((ext_vector_type(4))) float f32x4;

__device__ __forceinline__ float sigf(float x){ return 1.f/(1.f + expf(-x)); }

__device__ __forceinline__ unsigned short f2bf(float f){
  union { float f; unsigned u; } v; v.f = f;
  unsigned r = v.u + 0x7fff + ((v.u >> 16) & 1);
  return (unsigned short)(r >> 16);
}

// ---- LLC-coherent ops (device coherence point; bypass L1/L2, no allocate) ----
__device__ __forceinline__ void st_llc(float* p, float v){
  __hip_atomic_store(p, v, __ATOMIC_RELAXED, __HIP_MEMORY_SCOPE_AGENT);
}
__device__ __forceinline__ float ld_llc(const float* p){
  return __hip_atomic_load(p, __ATOMIC_RELAXED, __HIP_MEMORY_SCOPE_AGENT);
}
__device__ __forceinline__ void st_llc_u16(unsigned short* p, unsigned v){
  asm volatile("global_store_short %0, %1, off sc0 sc1" :: "v"(p), "v"(v) : "memory");
}
__device__ __forceinline__ void st_llc_u32(unsigned* p, unsigned v){
  asm volatile("global_store_dword %0, %1, off sc0 sc1" :: "v"(p), "v"(v) : "memory");
}
__device__ __forceinline__ void wait_vm0(){
  asm volatile("s_waitcnt vmcnt(0)" ::: "memory");
}

// Distributed-flag grid barrier, HOT-SPIN variant (best measured mechanism;
// atomic-RMW barriers corrupted twice and are condemned; per-step kernel
// launches cost ~10us each and lost). Each block owns a PRIVATE 128B line;
// arrival stores land in parallel across LLC banks. Poll: each WAVE
// independently hot-spins on its own 64 lines (load + vmcnt + __all; no
// sleep, no LDS, no per-iteration syncthreads), then one __syncthreads joins
// the 4 waves: monotonic flags => when the join passes, all 256 flags were
// seen >= p. Data crossing the barrier must use LLC ops (st_llc*) or be
// first-read-after-write; the entry vmcnt(0) drains this wave's outstanding
// stores before its lane-0 flag store. flags MUST be zeroed every launch.
__device__ __forceinline__ void flagbar(unsigned* flags, unsigned p){
  wait_vm0();
  __syncthreads();
  int tid = threadIdx.x;
  if (tid == 0)
    st_llc_u32(&flags[blockIdx.x*FSTRIDE], p);
  for (;;){
    unsigned v;
    asm volatile("global_load_dword %0, %1, off sc0 sc1"
                 : "=v"(v) : "v"(&flags[tid*FSTRIDE]));
    wait_vm0();
    if (__all((int)(v >= p))) break;
  }
  __syncthreads();
}

// ---------------------------------------------------------------------------
// Fused prelude: [0..NB_CVT) Wc fp32->bf16 cvt; [NB_CVT..NB_CVT+128) R1
// transpose tiles; [last] flag zeroing + zero row. All outputs disjoint.
__global__ __launch_bounds__(256) void k_pre(const float* __restrict__ Wc,
    unsigned short* __restrict__ Wc_bf, const float* __restrict__ R1,
    float* __restrict__ R1t, unsigned* __restrict__ flags,
    unsigned short* __restrict__ zrow){
  __shared__ float tz[32][33];
  int bid = blockIdx.x;
  int tid = threadIdx.x;
  if (bid < NB_CVT){
    int i = (bid*256 + tid)*4;
    float4 v = *(const float4*)(Wc + i);
    ushort4 o;
    o.x = f2bf(v.x); o.y = f2bf(v.y); o.z = f2bf(v.z); o.w = f2bf(v.w);
    *(ushort4*)(Wc_bf + i) = o;
  } else if (bid < NB_CVT + 128){
    int id = bid - NB_CVT;
    int bx = (id & 31)*32, by = (id >> 5)*32;   // bx over C=1024, by over R=128
    int x = tid & 31, y = tid >> 5;             // (32,8)
    #pragma unroll
    for (int i = 0; i < 32; i += 8){
      int r = by + y + i, c = bx + x;
      if (r < RANKH && c < HH) tz[y+i][x] = R1[(size_t)r*HH + c];
    }
    __syncthreads();
    #pragma unroll
    for (int i = 0; i < 32; i += 8){
      int r = bx + y + i, c = by + x;           // out dims [HH][RANKH]
      if (r < HH && c < RANKH) R1t[(size_t)r*RANKH + c] = tz[x][y+i];
    }
  } else {
    for (int i = tid; i < 2*FDOM; i += 256) flags[i] = 0u;
    for (int i = tid; i < 1024; i += 256) zrow[i] = 0;
  }
}

// ---------------------------------------------------------------------------
// Gx[m][n] = sum_k se[m][k]*Wih[n][k] + bih[n] + bhh[n]   (fp32 — decision path)
__global__ __launch_bounds__(256) void k_gemm_gx(const float* __restrict__ A,
    const float* __restrict__ Bw, const float* __restrict__ bih,
    const float* __restrict__ bhh, float* __restrict__ Cout, int M, int N, int K){
  __shared__ float as[16][68];
  __shared__ float bs[16][68];
  int m0 = blockIdx.x*64, n0 = blockIdx.y*64;
  int tid = threadIdx.x;
  int mt = tid & 15, nt = tid >> 4;
  float acc[4][4] = {};
  for (int k0 = 0; k0 < K; k0 += 16){
    #pragma unroll
    for (int it = 0; it < 4; ++it){
      int idx = it*256 + tid;
      int kk = idx & 15, mm = idx >> 4;
      as[kk][mm] = A[(size_t)(m0+mm)*K + k0 + kk];
      bs[kk][mm] = Bw[(size_t)(n0+mm)*K + k0 + kk];
    }
    __syncthreads();
    #pragma unroll
    for (int kk = 0; kk < 16; ++kk){
      float a4[4], b4[4];
      #pragma unroll
      for (int i = 0; i < 4; ++i) a4[i] = as[kk][mt*4+i];
      #pragma unroll
      for (int i = 0; i < 4; ++i) b4[i] = bs[kk][nt*4+i];
      #pragma unroll
      for (int i = 0; i < 4; ++i)
        #pragma unroll
        for (int j2 = 0; j2 < 4; ++j2) acc[i][j2] += a4[i]*b4[j2];
    }
    __syncthreads();
  }
  #pragma unroll
  for (int i = 0; i < 4; ++i){
    int m = m0 + mt*4 + i;
    #pragma unroll
    for (int j2 = 0; j2 < 4; ++j2){
      int n = n0 + nt*4 + j2;
      Cout[(size_t)m*N + n] = acc[i][j2] + bih[n] + bhh[n];
    }
  }
}

// ---------------------------------------------------------------------------
// Gx [m][t][4096] -> Gxt [t][4096][m]  (for coalesced per-step gate reads)
__global__ __launch_bounds__(256) void k_gx_t(const float* __restrict__ Gx,
                                              float* __restrict__ Gxt){
  __shared__ float t2[16][257];
  int t = blockIdx.x;       // 48
  int rc = blockIdx.y;      // 16 chunks of 256 rows
  int tid = threadIdx.x;
  #pragma unroll
  for (int m = 0; m < 16; ++m)
    t2[m][tid] = Gx[((size_t)(m*48 + t))*4096 + rc*256 + tid];
  __syncthreads();
  int rl = tid >> 4, m = tid & 15;
  #pragma unroll
  for (int i = 0; i < 16; ++i){
    int r = rc*256 + i*16 + rl;
    Gxt[((size_t)t*4096 + r)*16 + m] = t2[m][i*16 + rl];
  }
}

// ---------------------------------------------------------------------------
// Persistent LSTM scan: 256 blocks x 256 threads, 1 block/CU. Cross-step h
// via hx[t][j][m]: producer tail writes ONE contiguous 256B st_llc burst;
// consumers read the 64KB slab with contiguous cached dwordx4 (first-read-
// after-write -> fresh LLC lines, L2-shared per XCD), then LDS-transpose
// [j][m]->[m][j]. hs/cs/hs_bf are consumed by LATER KERNELS only -> plain
// cached stores issued AFTER the flag barrier (off the vmcnt drain / flag
// critical path; values carried across flagbar in registers). Reduce
// partials use stride RED_S=65 scalar writes (bank-step 1, conflict-free;
// the old stride-68 float4 writes were 8-way conflicted). Whh registers
// PERMUTED to the [m][k] layout:
//   lane kc owns k-indices {r*256 + 4*kc + j : r=0..3, j=0..3}
__global__ __launch_bounds__(256, 1) void k_lstm_scan(
    const float* __restrict__ Whh, const float* __restrict__ Gxt,
    float* __restrict__ hx,
    float* __restrict__ hs, float* __restrict__ cs,
    unsigned short* __restrict__ hs_bf, unsigned* __restrict__ flags){
  __shared__ float smem[17408];   // 68KB: h-stage [16][HS_S] / reduce partials [256][RED_S]
  __shared__ float gbuf[4*64];
  __shared__ float cbuf[64];
  int tid = threadIdx.x;
  int g = tid >> 6, kc = tid & 63;
  int j0 = blockIdx.x * 4;
  float w[4][16];
  #pragma unroll
  for (int jj = 0; jj < 4; ++jj){
    const float* src = Whh + (size_t)(g*1024 + j0 + jj)*1024 + kc*4;
    #pragma unroll
    for (int r = 0; r < 4; ++r){
      float4 v = *(const float4*)(src + r*256);
      w[jj][r*4+0]=v.x; w[jj][r*4+1]=v.y; w[jj][r*4+2]=v.z; w[jj][r*4+3]=v.w;
    }
  }
  if (tid < 64) cbuf[tid] = 0.f;
  for (int t = 0; t < LL; ++t){
    float gx = Gxt[((size_t)t*NG4 + g*1024 + j0 + (kc & 3))*16 + (kc >> 2)];
    float G = 0.f;
    if (t > 0){
      const float* slab = hx + (size_t)(t-1)*16384;
      f32x4 hv[16];
      #pragma unroll
      for (int i = 0; i < 16; ++i)
        hv[i] = *(const f32x4*)(slab + i*1024 + tid*4);
      {
        int mb = (tid & 3) * 4;
        int jb = tid >> 2;
        #pragma unroll
        for (int i = 0; i < 16; ++i){
          #pragma unroll
          for (int e = 0; e < 4; ++e)
            smem[(size_t)(mb + e)*HS_S + i*64 + jb] = hv[i][e];
        }
      }
      __syncthreads();
      float acc[4][16];
      #pragma unroll 4
      for (int m = 0; m < 16; ++m){
        const float* hb = &smem[(size_t)m*HS_S + (kc<<2)];
        float4 h0 = *(const float4*)(hb);
        float4 h1 = *(const float4*)(hb+256);
        float4 h2 = *(const float4*)(hb+512);
        float4 h3 = *(const float4*)(hb+768);
        #pragma unroll
        for (int jj = 0; jj < 4; ++jj){
          float s = w[jj][0]*h0.x + w[jj][1]*h0.y + w[jj][2]*h0.z + w[jj][3]*h0.w
                  + w[jj][4]*h1.x + w[jj][5]*h1.y + w[jj][6]*h1.z + w[jj][7]*h1.w
                  + w[jj][8]*h2.x + w[jj][9]*h2.y + w[jj][10]*h2.z + w[jj][11]*h2.w
                  + w[jj][12]*h3.x + w[jj][13]*h3.y + w[jj][14]*h3.z + w[jj][15]*h3.w;
          acc[jj][m] = s;
        }
      }
      __syncthreads();   // h reads done; smem reused as reduce partials
      #pragma unroll
      for (int m = 0; m < 16; ++m){
        #pragma unroll
        for (int jj = 0; jj < 4; ++jj)
          smem[(size_t)(g*64 + kc)*RED_S + m*4 + jj] = acc[jj][m];
      }
      __syncthreads();
      {
        float s0=0.f,s1=0.f,s2=0.f,s3=0.f;
        #pragma unroll 4
        for (int l = 0; l < 64; l += 4){
          s0 += smem[(size_t)(g*64 + l  )*RED_S + kc];
          s1 += smem[(size_t)(g*64 + l+1)*RED_S + kc];
          s2 += smem[(size_t)(g*64 + l+2)*RED_S + kc];
          s3 += smem[(size_t)(g*64 + l+3)*RED_S + kc];
        }
        G = (s0+s1)+(s2+s3);
      }
    }
    gbuf[g*64 + kc] = G + gx;
    __syncthreads();
    float hval = 0.f, cval = 0.f;
    size_t oidx = 0;
    if (g == 0){
      int o = kc;                       // o = jj*16 + m (coalesced hx order)
      int jj = o >> 4, m = o & 15;
      int op = m*4 + jj;
      float gi = gbuf[0*64 + op];
      float gf = gbuf[1*64 + op];
      float gu = gbuf[2*64 + op];
      float go = gbuf[3*64 + op];
      float cp = cbuf[op];
      cval = sigf(gf)*cp + sigf(gi)*tanhf(gu);
      hval = sigf(go)*tanhf(cval);
      cbuf[op] = cval;
      // cross-step exchange: ONE contiguous 256B st_llc burst per block
      st_llc(&hx[(size_t)t*16384 + j0*16 + o], hval);
      oidx = ((size_t)(m*LL + t))*HH + j0 + jj;
    }
    if (t < LL-1)
      flagbar(flags, (unsigned)(t+1));
    // downstream-only outputs AFTER the barrier: off the flag critical path
    if (g == 0){
      hs[oidx] = hval;
      cs[oidx] = cval;
      hs_bf[oidx] = f2bf(hval);
    }
  }
}

// ---------------------------------------------------------------------------
// Per-position rank-MLP score + gumbel noise (fp32 — decision path).
__global__ __launch_bounds__(128) void k_score(const float* __restrict__ R1t,
    const float* __restrict__ R2, const float* __restrict__ hs,
    const float* __restrict__ gumbel_u, float* __restrict__ score,
    float* __restrict__ snoisy){
  __shared__ float hsm[HH];
  __shared__ float red[128];
  int bt = blockIdx.x;
  int tid = threadIdx.x;
  for (int i = tid; i < HH; i += 128) hsm[i] = hs[(size_t)bt*HH + i];
  __syncthreads();
  float acc = 0.f;
  for (int k = 0; k < HH; ++k) acc += R1t[(size_t)k*RANKH + tid] * hsm[k];
  red[tid] = fmaxf(acc, 0.f) * R2[tid];
  __syncthreads();
  for (int s = 64; s > 0; s >>= 1){
    if (tid < s) red[tid] += red[tid+s];
    __syncthreads();
  }
  if (tid == 0){
    float s = red[0];
    float u = gumbel_u[bt];
    float noise = -logf(-logf(u));
    score[bt]  = s;
    snoisy[bt] = s + noise;
  }
}

// ---------------------------------------------------------------------------
// Build the tree structure for all batches. 1 block, 64 threads.
// level_count[0] <- number of levels (max height).
__global__ __launch_bounds__(64) void k_build(const float* __restrict__ score,
    const float* __restrict__ snoisy, const int* __restrict__ length,
    int* __restrict__ node_l, int* __restrict__ node_r, int* __restrict__ node_x,
    int* __restrict__ node_lvl, int* __restrict__ node_b, int* __restrict__ node_root,
    int* __restrict__ level_count, int* __restrict__ level_off, int* __restrict__ order){
  __shared__ float sc[BB*LL], sn[BB*LL];
  __shared__ int lcount[MAXLVL+1], lcur[MAXLVL+1], loff[MAXLVL+1];
  __shared__ int percnt[BB];
  int tid = threadIdx.x;
  for (int i = tid; i < BB*LL; i += 64){ sc[i] = score[i]; sn[i] = snoisy[i]; }
  for (int i = tid; i <= MAXLVL; i += 64){ lcount[i] = 0; lcur[i] = 0; }
  __syncthreads();
  if (tid < BB){
    int b = tid;
    int len = length[b];
    if (len > LL) len = LL;
    int qs[MAXN], qe[MAXN], qn[MAXN];
    int qh = 0, qt = 0, cnt = 0;
    int rootn = cnt++;
    qs[qt] = 0; qe[qt] = len; qn[qt] = rootn; qt++;
    while (qh < qt){
      int s0 = qs[qh], e0 = qe[qh], nid = qn[qh]; qh++;
      float best = sc[b*LL + s0]; int pos = s0;
      for (int t2 = s0+1; t2 < e0; ++t2){
        float v = sc[b*LL + t2];
        if (v > best){ best = v; pos = t2; }
      }
      float bestn = sn[b*LL + s0]; int js = s0;
      for (int t2 = s0+1; t2 < e0; ++t2){
        float v = sn[b*LL + t2];
        if (v > bestn){ bestn = v; js = t2; }
      }
      int gid = b*MAXN + nid;
      node_x[gid] = js;
      node_b[gid] = b;
      node_root[gid] = (nid == 0) ? 1 : 0;
      int ln = pos - s0, enc_l, enc_r;
      if (ln <= 0) enc_l = -1;
      else if (ln == 1) enc_l = 10000 + s0;
      else { int c2 = cnt++; enc_l = b*MAXN + c2; qs[qt]=s0; qe[qt]=pos; qn[qt]=c2; qt++; }
      int rn = e0 - (pos+1);
      if (rn <= 0) enc_r = -1;
      else if (rn == 1) enc_r = 10000 + (pos+1);
      else { int c2 = cnt++; enc_r = b*MAXN + c2; qs[qt]=pos+1; qe[qt]=e0; qn[qt]=c2; qt++; }
      node_l[gid] = enc_l; node_r[gid] = enc_r;
    }
    for (int i = cnt-1; i >= 0; --i){
      int gid = b*MAXN + i;
      int el = node_l[gid], er = node_r[gid];
      int llv = (el >= 0 && el < 10000) ? node_lvl[el] : 0;
      int rlv = (er >= 0 && er < 10000) ? node_lvl[er] : 0;
      node_lvl[gid] = 1 + (llv > rlv ? llv : rlv);
    }
    for (int i = 0; i < cnt; ++i) atomicAdd(&lcount[node_lvl[b*MAXN + i]], 1);
    percnt[b] = cnt;
  }
  __syncthreads();
  if (tid == 0){
    int off = 0, nlev = 0;
    for (int lv = 1; lv <= MAXLVL; ++lv){
      loff[lv] = off;
      level_off[lv] = off;
      level_count[lv] = lcount[lv];
      if (lcount[lv] > 0) nlev = lv;
      off += lcount[lv];
    }
    level_count[0] = nlev;
  }
  __syncthreads();
  if (tid < BB){
    int b = tid;
    int cnt = percnt[b];
    for (int i = 0; i < cnt; ++i){
      int gid = b*MAXN + i;
      int lv = node_lvl[gid];
      int p = atomicAdd(&lcur[lv], 1);
      order[loff[lv] + p] = gid;
    }
  }
}

// ---------------------------------------------------------------------------
// Persistent tree composition, hot-spin flag barriers, NO wb/inv.
// Wc is LDS-RESIDENT: each of the 256 blocks owns 24 Wc rows (144KB, loaded
// once, XOR-swizzled). Per level every block computes its 24 gate columns for
// ALL nodes of the level; A-frags are L2-broadcast reads, B from LDS.
// Coherence protocol:
//  - gates: LLC stores (A) -> LLC loads (B)
//  - nodeH_bf / nodeC: LLC stores (B) -> normal cached first-reads later
//  - Wc_bf / hs_bf / order / node_*: read-only, cached.
__global__ __launch_bounds__(256, 1) void k_tree(
    const unsigned short* __restrict__ Wc_bf,
    const unsigned short* __restrict__ hs_bf,
    unsigned short* __restrict__ nodeH_bf,
    const unsigned short* __restrict__ zrow,
    const float* __restrict__ bc, const float* __restrict__ cs,
    float* __restrict__ nodeC,
    const int* __restrict__ node_l, const int* __restrict__ node_r,
    const int* __restrict__ node_x, const int* __restrict__ node_b,
    const int* __restrict__ node_root, const int* __restrict__ level_count,
    const int* __restrict__ level_off, const int* __restrict__ order,
    float* __restrict__ gates, float* __restrict__ out,
    unsigned* __restrict__ flags){
  __shared__ __align__(16) unsigned char wlds[24*6144];   // 144KB Wc slice
  int tid = threadIdx.x;
  int lane = tid & 63;
  int wave = tid >> 6;
  int fr = lane & 15;          // fragment row (A: node slot, B: Wc row)
  int fkq = lane >> 4;         // k-quarter 0..3
  int fk  = fkq * 8;           // element offset within 32-elem k-chunk
  int fkb = fkq * 16;          // byte offset
  int swz = (fr & 7) << 4;     // XOR swizzle (G4: row-major stride-6144B tile)
  int base0 = fr * 6144;               // n-tile 0: rows 0..15
  int base1 = (16 + (fr & 7)) * 6144;  // n-tile 1: rows 16..23 (dup for fr>=8)
  int rg24 = blockIdx.x * 24;  // this block's 24 Wc rows / gate columns

  // ---- one-time: stage 24 Wc rows into LDS, swizzled ----
  for (int i = tid; i < 24*384; i += 256){
    int row = i / 384;
    int ch  = i - row*384;     // 16B chunk within row
    uint4 v = *(const uint4*)(Wc_bf + (size_t)(rg24 + row)*K3H + ch*8);
    *(uint4*)(wlds + row*6144 + ((ch*16) ^ ((row & 7) << 4))) = v;
  }
  __syncthreads();

  int nlev = level_count[0];
  unsigned ph = 0;
  for (int lvl = 1; lvl <= nlev; ++lvl){
    int n = level_count[lvl];
    int loffv = level_off[lvl];
    // ---- Phase A: all nodes x this block's 24 Wc rows, B from LDS ----
    int mtiles = (n + 15) >> 4;
    for (int mt = wave; mt < mtiles; mt += 4){
      int slot = mt*16 + fr;
      const unsigned short *pa0, *pa1, *pa2;
      if (slot < n){
        int gid = order[loffv + slot];
        int b = node_b[gid];
        int el = node_l[gid], er = node_r[gid], xt = node_x[gid];
        pa0 = (el < 0) ? zrow : (el >= 10000 ? hs_bf + (size_t)(b*LL + (el-10000))*HH
                                             : nodeH_bf + (size_t)el*HH);
        pa1 = (er < 0) ? zrow : (er >= 10000 ? hs_bf + (size_t)(b*LL + (er-10000))*HH
                                             : nodeH_bf + (size_t)er*HH);
        pa2 = hs_bf + (size_t)(b*LL + xt)*HH;
      } else { pa0 = zrow; pa1 = zrow; pa2 = zrow; }
      const unsigned short* pa[3] = {pa0, pa1, pa2};
      f32x4 acc0 = {0.f,0.f,0.f,0.f};
      f32x4 acc1 = {0.f,0.f,0.f,0.f};
      #pragma unroll
      for (int part = 0; part < 3; ++part){
        const unsigned short* ap = pa[part] + fk;
        #pragma unroll 8
        for (int kcc = 0; kcc < 1024; kcc += 32){
          bf16x8 a = *(const bf16x8*)(ap + kcc);
          int xb = part*2048 + kcc*2 + fkb;
          bf16x8 b0 = *(const bf16x8*)(wlds + base0 + (xb ^ swz));
          bf16x8 b1 = *(const bf16x8*)(wlds + base1 + (xb ^ swz));
          acc0 = __builtin_amdgcn_mfma_f32_16x16x32_bf16(a, b0, acc0, 0, 0, 0);
          acc1 = __builtin_amdgcn_mfma_f32_16x16x32_bf16(a, b1, acc1, 0, 0, 0);
        }
      }
      int m0 = mt*16 + fkq*4;
      #pragma unroll
      for (int r = 0; r < 4; ++r){
        int m = m0 + r;
        if (m < n){
          st_llc(&gates[(size_t)m*NG6 + rg24 + fr], acc0[r]);
          if (fr < 8)
            st_llc(&gates[(size_t)m*NG6 + rg24 + 16 + fr], acc1[r]);
        }
      }
    }
    ph++;
    flagbar(flags, ph);
    // ---- Phase B: epilogue ----
    int items = n * 4;
    for (int it = blockIdx.x; it < items; it += 256){
      int ns = it >> 2;
      int j = (it & 3)*256 + tid;
      int gid = order[loffv + ns];
      int b = node_b[gid];
      int el = node_l[gid], er = node_r[gid], xt = node_x[gid];
      float gg[6];
      #pragma unroll
      for (int q = 0; q < 6; ++q)
        gg[q] = bc[q*HH + j] + ld_llc(&gates[(size_t)ns*NG6 + q*HH + j]);
      float lc = (el < 0) ? 0.f : (el >= 10000 ? cs[(size_t)(b*LL + (el-10000))*HH + j]
                                               : nodeC[(size_t)el*HH + j]);
      float rc = (er < 0) ? 0.f : (er >= 10000 ? cs[(size_t)(b*LL + (er-10000))*HH + j]
                                               : nodeC[(size_t)er*HH + j]);
      float xc = cs[(size_t)(b*LL + xt)*HH + j];
      float c = sigf(gg[0])*tanhf(gg[4]) + sigf(gg[1])*lc + sigf(gg[2])*rc + sigf(gg[3])*xc;
      float h = sigf(gg[5])*tanhf(c);
      st_llc_u16(&nodeH_bf[(size_t)gid*HH + j], (unsigned)f2bf(h));
      st_llc(&nodeC[(size_t)gid*HH + j], c);
      if (node_root[gid]){
        out[(size_t)b*HH + j] = h;
        out[(size_t)BB*HH + (size_t)b*HH + j] = c;
      }
    }
    if (lvl < nlev){
      ph++;
      flagbar(flags, ph);
    }
  }
}

// ---------------------------------------------------------------------------
extern "C" void kernel_launch(void* const* d_in, const int* in_sizes, int n_in,
                              void* d_out, int out_size, void* d_ws, size_t ws_size,
                              hipStream_t stream){
  const float* se  = (const float*)d_in[0];
  const float* gu  = (const float*)d_in[1];
  const float* Wih = (const float*)d_in[2];
  const float* Whh = (const float*)d_in[3];
  const float* bih = (const float*)d_in[4];
  const float* bhh = (const float*)d_in[5];
  const float* R1  = (const float*)d_in[6];
  const float* R2  = (const float*)d_in[7];
  const float* Wc  = (const float*)d_in[8];
  const float* bc  = (const float*)d_in[9];
  const int*   len = (const int*)d_in[10];
  float* out = (float*)d_out;                 // [2,16,1024] fp32

  float* ws = (float*)d_ws;
  size_t off = 0;
  float* R1t   = ws + off; off += (size_t)HH*RANKH;
  float* Gx    = ws + off; off += (size_t)BB*LL*NG4;     // [m][t][4096]
  float* Gxt   = ws + off; off += (size_t)BB*LL*NG4;     // [t][4096][m]
  float* hx    = ws + off; off += (size_t)LL*HH*BB;      // [t][j][m] exchange (3MB)
  float* hs    = ws + off; off += (size_t)BB*LL*HH;
  float* cs    = ws + off; off += (size_t)BB*LL*HH;
  float* nodeC = ws + off; off += (size_t)TOTN*HH;
  float* gates = ws + off; off += (size_t)MAXNPL*NG6;
  unsigned short* Wc_bf    = (unsigned short*)(ws + off); off += (size_t)NG6*K3H/2;
  unsigned short* hs_bf    = (unsigned short*)(ws + off); off += (size_t)BB*LL*HH/2;
  unsigned short* nodeH_bf = (unsigned short*)(ws + off); off += (size_t)TOTN*HH/2 + 512;
  unsigned short* zrow     = (unsigned short*)(ws + off); off += 512;  // 1024 zero bf16
  float* score = ws + off; off += 1024;
  float* snoi  = ws + off; off += 1024;
  unsigned* flags = (unsigned*)(ws + off); off += 2*FDOM; // scan @0, tree @ +FDOM dwords
  int* ib = (int*)(ws + off);
  int* node_l    = ib; ib += 768;
  int* node_r    = ib; ib += 768;
  int* node_x    = ib; ib += 768;
  int* node_lvl  = ib; ib += 768;
  int* node_b    = ib; ib += 768;
  int* node_root = ib; ib += 768;
  int* level_count = ib; ib += 64;
  int* level_off   = ib; ib += 64;
  int* order       = ib; ib += 768;

  // 0. fused prelude: Wc cvt + R1 transpose + flag/zrow init (one launch)
  k_pre<<<NB_CVT + 128 + 1, 256, 0, stream>>>(Wc, Wc_bf, R1, R1t, flags, zrow);
  // 1. input-side gate GEMM (+ both biases), then transpose for the scan
  k_gemm_gx<<<dim3(12, 64), 256, 0, stream>>>(se, Wih, bih, bhh, Gx, BB*LL, NG4, HH);
  k_gx_t<<<dim3(48, 16), 256, 0, stream>>>(Gx, Gxt);
  // 2. persistent recurrent LSTM scan (48 steps, hot-spin flag barriers)
  k_lstm_scan<<<256, 256, 0, stream>>>(Whh, Gxt, hx, hs, cs, hs_bf, flags);
  // 3. per-position scores + gumbel noise (fp32)
  k_score<<<BB*LL, 128, 0, stream>>>(R1t, R2, hs, gu, score, snoi);
  // 4. tree structure
  k_build<<<1, 64, 0, stream>>>(score, snoi, len, node_l, node_r, node_x,
                                node_lvl, node_b, node_root,
                                level_count, level_off, order);
  // 5. persistent level-by-level nary composition (hot-spin flag barriers)
  k_tree<<<256, 256, 0, stream>>>(Wc_bf, hs_bf, nodeH_bf, zrow, bc, cs, nodeC,
                                  node_l, node_r, node_x, node_b, node_root,
                                  level_count, level_off, order,
                                  gates, out, flags + FDOM);
}